// Round 4
// baseline (255.892 us; speedup 1.0000x reference)
//
#include <hip/hip_runtime.h>
#include <hip/hip_fp16.h>

#define NN 50000
#define NE 800000
#define NB_C ((NN + 255) / 256)   // 196 chunks of 256

// bucket sort params
#define NB 128
#define BRANGE 391                 // ceil(NN/NB), NB*BRANGE = 50048 >= NN
#define SCAP 8192                  // staging capacity per bucket (avg 6250, +24 sigma)
#define CHUNK 6144                 // edges per sortA block
#define NBLK_A ((NE + CHUNK - 1) / CHUNK)

// ---------------- CSR build ----------------

__global__ __launch_bounds__(256) void init_counts_k(int* counts, int* gcur) {
    int i = blockIdx.x * 256 + threadIdx.x;
    if (i < NN) counts[i] = 0;
    if (i < NB) gcur[i] = 0;
}

__global__ __launch_bounds__(256) void hist_k(const int* __restrict__ dst, int* __restrict__ counts) {
    int e = blockIdx.x * 256 + threadIdx.x;
    if (e < NE) atomicAdd(&counts[dst[e]], 1);
}

__global__ __launch_bounds__(256) void partial_k(const int* __restrict__ counts, int* __restrict__ bsum) {
    __shared__ int ws[4];
    const int t = threadIdx.x, i = blockIdx.x * 256 + t;
    int s = (i < NN) ? counts[i] : 0;
    #pragma unroll
    for (int m = 1; m < 64; m <<= 1) s += __shfl_xor(s, m, 64);
    if ((t & 63) == 0) ws[t >> 6] = s;
    __syncthreads();
    if (t == 0) bsum[blockIdx.x] = ws[0] + ws[1] + ws[2] + ws[3];
}

__global__ __launch_bounds__(256) void scanb_k(const int* __restrict__ bsum,
                                               int* __restrict__ boff,
                                               int* __restrict__ offs_last) {
    __shared__ int wsum[4];
    const int t = threadIdx.x, lane = t & 63, wid = t >> 6;
    const int v = (t < NB_C) ? bsum[t] : 0;
    int s = v;
    #pragma unroll
    for (int off = 1; off < 64; off <<= 1) {
        int tv = __shfl_up(s, off, 64);
        if (lane >= off) s += tv;
    }
    if (lane == 63) wsum[wid] = s;
    __syncthreads();
    int add = 0;
    for (int w = 0; w < wid; w++) add += wsum[w];
    const int excl = s - v + add;
    if (t < NB_C) boff[t] = excl;
    if (t == NB_C - 1) offs_last[0] = excl + v;
}

__global__ __launch_bounds__(256) void offs_k(const int* __restrict__ counts,
                                              const int* __restrict__ boff,
                                              int* __restrict__ offs) {
    __shared__ int wsum[4];
    const int t = threadIdx.x, lane = t & 63, wid = t >> 6;
    const int i = blockIdx.x * 256 + t;
    const int v = (i < NN) ? counts[i] : 0;
    int s = v;
    #pragma unroll
    for (int off = 1; off < 64; off <<= 1) {
        int tv = __shfl_up(s, off, 64);
        if (lane >= off) s += tv;
    }
    if (lane == 63) wsum[wid] = s;
    __syncthreads();
    int add = boff[blockIdx.x];
    for (int w = 0; w < wid; w++) add += wsum[w];
    const int excl = s - v + add;
    if (i < NN) offs[i] = excl;
}

// ---- sort pass A: bin edges into bucket-contiguous staging (LDS local sort + burst flush)
__global__ __launch_bounds__(256) void sortA_k(const int* __restrict__ src,
                                               const int* __restrict__ dst,
                                               const float* __restrict__ wE,
                                               int* __restrict__ gcur,
                                               int2* __restrict__ stage) {
    __shared__ int hcnt[NB], lexcl[NB], lcur[NB], gbase[NB];
    __shared__ int2 lbuf[CHUNK];
    const int t = threadIdx.x;
    const int e0 = blockIdx.x * CHUNK;
    const int ne = min(CHUNK, NE - e0);
    for (int i = t; i < NB; i += 256) { hcnt[i] = 0; lcur[i] = 0; }
    __syncthreads();
    for (int i = t; i < ne; i += 256) {
        const int b = dst[e0 + i] / BRANGE;
        atomicAdd(&hcnt[b], 1);
    }
    __syncthreads();
    if (t < 64) {   // wave-0 scan, 2 entries per lane
        const int v0 = hcnt[2 * t], v1 = hcnt[2 * t + 1];
        const int s = v0 + v1;
        int inc = s;
        #pragma unroll
        for (int off = 1; off < 64; off <<= 1) {
            int u = __shfl_up(inc, off, 64);
            if (t >= off) inc += u;
        }
        const int excl = inc - s;
        lexcl[2 * t] = excl;
        lexcl[2 * t + 1] = excl + v0;
    }
    __syncthreads();
    if (t < NB && hcnt[t] > 0) gbase[t] = atomicAdd(&gcur[t], hcnt[t]);
    __syncthreads();
    for (int i = t; i < ne; i += 256) {
        const int d = dst[e0 + i];
        const int b = d / BRANGE;
        const int r = atomicAdd(&lcur[b], 1);
        const int dloc = d - b * BRANGE;
        lbuf[lexcl[b] + r] = make_int2(src[e0 + i] | (dloc << 16), __float_as_int(wE[e0 + i]));
    }
    __syncthreads();
    for (int b = 0; b < NB; b++) {
        const int cnt = hcnt[b], lo = lexcl[b];
        int2* dp = stage + (size_t)b * SCAP + gbase[b];
        for (int j = t; j < cnt; j += 256) dp[j] = lbuf[lo + j];
    }
}

// ---- sort pass B: one block per bucket, scatter to final CSR (single-writer lines)
__global__ __launch_bounds__(256) void sortB_k(const int* __restrict__ gcur,
                                               const int2* __restrict__ stage,
                                               const int* __restrict__ offs,
                                               int2* __restrict__ csr) {
    __shared__ int lcur[BRANGE];
    const int b = blockIdx.x, t = threadIdx.x;
    for (int i = t; i < BRANGE; i += 256) lcur[i] = 0;
    __syncthreads();
    const int nb = gcur[b];
    const int dlo = b * BRANGE;
    const int2* sp = stage + (size_t)b * SCAP;
    for (int i = t; i < nb; i += 256) {
        const int2 pr = sp[i];
        const int dloc = (pr.x >> 16) & 0x1FF;
        const int sv = pr.x & 0xFFFF;
        const int r = atomicAdd(&lcur[dloc], 1);
        csr[offs[dlo + dloc] + r] = make_int2(sv, pr.y);
    }
}

// ---------------- Layer 1 projection ----------------
// 256 threads: tx=t&31 (cols tx+32q, q=0..3), ty=t>>5 (nodes 8ty..8ty+7). 64 nodes/block.
__global__ __launch_bounds__(256) void proj1_k(const float* __restrict__ x,
                                               const float* __restrict__ W1,
                                               const float* __restrict__ al1,
                                               const float* __restrict__ ar1,
                                               __half* __restrict__ h1h,
                                               float* __restrict__ el1,
                                               float* __restrict__ er1) {
    __shared__ float xs[64 * 128];   // [node][k], 32 KB
    const int t = threadIdx.x, tx = t & 31, ty = t >> 5;
    const int n0 = blockIdx.x * 64;
    const int nvalid = min(64, NN - n0);
    float4* xs4 = (float4*)xs;
    for (int i = t; i < 2048; i += 256) {
        const int nn = i >> 5, k4 = i & 31;
        float4 v = make_float4(0.f, 0.f, 0.f, 0.f);
        if (nn < nvalid) v = ((const float4*)(x + (size_t)(n0 + nn) * 128))[k4];
        xs4[nn * 32 + k4] = v;
    }
    __syncthreads();

    float acc[4][8];
    #pragma unroll
    for (int q = 0; q < 4; q++)
        #pragma unroll
        for (int nn = 0; nn < 8; nn++) acc[q][nn] = 0.f;

    const float* xrow = xs + ty * 8 * 128;
    for (int k4 = 0; k4 < 32; k4++) {
        float wv[4][4];
        #pragma unroll
        for (int kk = 0; kk < 4; kk++)
            #pragma unroll
            for (int q = 0; q < 4; q++)
                wv[q][kk] = W1[(size_t)(k4 * 4 + kk) * 128 + tx + 32 * q];
        #pragma unroll
        for (int nn = 0; nn < 8; nn++) {
            const float4 xv = *(const float4*)(xrow + nn * 128 + k4 * 4);
            #pragma unroll
            for (int q = 0; q < 4; q++)
                acc[q][nn] = fmaf(xv.x, wv[q][0], fmaf(xv.y, wv[q][1],
                             fmaf(xv.z, wv[q][2], fmaf(xv.w, wv[q][3], acc[q][nn]))));
        }
    }

    float av[4], rv[4];
    #pragma unroll
    for (int q = 0; q < 4; q++) { av[q] = al1[tx + 32 * q]; rv[q] = ar1[tx + 32 * q]; }

    #pragma unroll
    for (int nn = 0; nn < 8; nn++) {
        const int n = n0 + ty * 8 + nn;
        const bool ok = (n < NN);
        #pragma unroll
        for (int q = 0; q < 4; q++) {
            if (ok) h1h[(size_t)n * 128 + tx + 32 * q] = __float2half(acc[q][nn]);
            float pe = acc[q][nn] * av[q];
            float pr = acc[q][nn] * rv[q];
            #pragma unroll
            for (int m = 1; m < 16; m <<= 1) {
                pe += __shfl_xor(pe, m, 64);
                pr += __shfl_xor(pr, m, 64);
            }
            if (ok && (tx & 15) == 0) {
                const int h = (q << 1) | (tx >> 4);
                el1[(size_t)n * 8 + h] = pe;
                er1[(size_t)n * 8 + h] = pr;
            }
        }
    }
}

// ---------------- Layer 1 aggregation: one wave per dst node ----------------
__global__ __launch_bounds__(128) void agg1_k(const int* __restrict__ offs,
                                              const int2* __restrict__ csr,
                                              const __half* __restrict__ h1h,
                                              const float* __restrict__ el1,
                                              const float* __restrict__ er1,
                                              const float* __restrict__ b1,
                                              float* __restrict__ h2in) {
    const int t = threadIdx.x, w = t >> 6, l = t & 63;
    const int n = blockIdx.x * 2 + w;
    const int beg = offs[n], deg = offs[n + 1] - beg;
    __shared__ int   lsrc[2][16];
    __shared__ float lw[2][16];
    __shared__ float pw[2][128];
    const int h = l & 7, g = l & 15, es = l >> 4, hg = g >> 1;
    const int e0 = l >> 3, e1 = e0 + 8;
    const float er_h = er1[(size_t)n * 8 + h];
    float m_run = -1e30f, z_run = 0.f;
    float acc[8];
    #pragma unroll
    for (int j = 0; j < 8; j++) acc[j] = 0.f;
    const float4* hp4 = (const float4*)h1h;

    for (int base = 0; base < deg; base += 16) {
        if (l < 16) {
            int2 pr = (base + l < deg) ? csr[beg + base + l] : make_int2(0, 0);
            lsrc[w][l] = pr.x;
            lw[w][l] = __int_as_float(pr.y);
        }
        asm volatile("" ::: "memory");
        float lg0 = -1e30f, lg1 = -1e30f;
        if (base + e0 < deg) {
            const float v = el1[(size_t)lsrc[w][e0] * 8 + h] + er_h;
            lg0 = v > 0.f ? v : 0.2f * v;
        }
        if (base + e1 < deg) {
            const float v = el1[(size_t)lsrc[w][e1] * 8 + h] + er_h;
            lg1 = v > 0.f ? v : 0.2f * v;
        }
        float tm = fmaxf(lg0, lg1);
        tm = fmaxf(tm, __shfl_xor(tm, 8, 64));
        tm = fmaxf(tm, __shfl_xor(tm, 16, 64));
        tm = fmaxf(tm, __shfl_xor(tm, 32, 64));
        const float m_new = fmaxf(m_run, tm);
        const float sc = __expf(m_run - m_new);
        const float p0 = __expf(lg0 - m_new);
        const float p1 = __expf(lg1 - m_new);
        float za = p0 + p1;
        za += __shfl_xor(za, 8, 64);
        za += __shfl_xor(za, 16, 64);
        za += __shfl_xor(za, 32, 64);
        z_run = z_run * sc + za;
        m_run = m_new;
        pw[w][l] = p0 * lw[w][e0];
        pw[w][l + 64] = p1 * lw[w][e1];
        asm volatile("" ::: "memory");
        const float scg = __shfl(sc, hg, 8);
        #pragma unroll
        for (int j = 0; j < 8; j++) acc[j] *= scg;
        const int sA = lsrc[w][es], sB = lsrc[w][es + 4], sC = lsrc[w][es + 8], sD = lsrc[w][es + 12];
        const float pA = pw[w][es * 8 + hg], pB = pw[w][(es + 4) * 8 + hg];
        const float pC = pw[w][(es + 8) * 8 + hg], pD = pw[w][(es + 12) * 8 + hg];
        const float4 vA = hp4[(size_t)sA * 16 + g];
        const float4 vB = hp4[(size_t)sB * 16 + g];
        const float4 vC = hp4[(size_t)sC * 16 + g];
        const float4 vD = hp4[(size_t)sD * 16 + g];
        #pragma unroll
        for (int q = 0; q < 4; q++) {
            const __half2 hA = ((const __half2*)&vA)[q];
            const __half2 hB = ((const __half2*)&vB)[q];
            const __half2 hC = ((const __half2*)&vC)[q];
            const __half2 hD = ((const __half2*)&vD)[q];
            const float2 fA = __half22float2(hA), fB = __half22float2(hB);
            const float2 fC = __half22float2(hC), fD = __half22float2(hD);
            acc[2 * q]     = fmaf(pA, fA.x, fmaf(pB, fB.x, fmaf(pC, fC.x, fmaf(pD, fD.x, acc[2 * q]))));
            acc[2 * q + 1] = fmaf(pA, fA.y, fmaf(pB, fB.y, fmaf(pC, fC.y, fmaf(pD, fD.y, acc[2 * q + 1]))));
        }
        asm volatile("" ::: "memory");
    }
    #pragma unroll
    for (int j = 0; j < 8; j++) {
        acc[j] += __shfl_xor(acc[j], 16, 64);
        acc[j] += __shfl_xor(acc[j], 32, 64);
    }
    const float zg = __shfl(z_run, hg, 8);
    if (l < 16) {
        const float inv = (deg > 0) ? 1.f / zg : 0.f;
        const float4* b4 = (const float4*)b1;
        const float4 bb0 = b4[g * 2], bb1 = b4[g * 2 + 1];
        float4 o0, o1;
        o0.x = fmaxf(acc[0] * inv + bb0.x, 0.f);
        o0.y = fmaxf(acc[1] * inv + bb0.y, 0.f);
        o0.z = fmaxf(acc[2] * inv + bb0.z, 0.f);
        o0.w = fmaxf(acc[3] * inv + bb0.w, 0.f);
        o1.x = fmaxf(acc[4] * inv + bb1.x, 0.f);
        o1.y = fmaxf(acc[5] * inv + bb1.y, 0.f);
        o1.z = fmaxf(acc[6] * inv + bb1.z, 0.f);
        o1.w = fmaxf(acc[7] * inv + bb1.w, 0.f);
        float4* op = (float4*)(h2in + (size_t)n * 128 + g * 8);
        op[0] = o0; op[1] = o1;
    }
}

// ---------------- Layer 2 projection ----------------
// 256 threads: tx=t&31 (cols tx, tx+32), ty=t>>5 (nodes 8ty..8ty+7). 64 nodes/block.
__global__ __launch_bounds__(256) void proj2_k(const float* __restrict__ x,
                                               const float* __restrict__ W2,
                                               const float* __restrict__ al2,
                                               const float* __restrict__ ar2,
                                               __half* __restrict__ h2h,
                                               float* __restrict__ el2,
                                               float* __restrict__ er2) {
    __shared__ float xs[64 * 128];
    const int t = threadIdx.x, tx = t & 31, ty = t >> 5;
    const int n0 = blockIdx.x * 64;
    const int nvalid = min(64, NN - n0);
    float4* xs4 = (float4*)xs;
    for (int i = t; i < 2048; i += 256) {
        const int nn = i >> 5, k4 = i & 31;
        float4 v = make_float4(0.f, 0.f, 0.f, 0.f);
        if (nn < nvalid) v = ((const float4*)(x + (size_t)(n0 + nn) * 128))[k4];
        xs4[nn * 32 + k4] = v;
    }
    __syncthreads();

    float acc[2][8];
    #pragma unroll
    for (int q = 0; q < 2; q++)
        #pragma unroll
        for (int nn = 0; nn < 8; nn++) acc[q][nn] = 0.f;

    const float* xrow = xs + ty * 8 * 128;
    for (int k4 = 0; k4 < 32; k4++) {
        float wv[2][4];
        #pragma unroll
        for (int kk = 0; kk < 4; kk++)
            #pragma unroll
            for (int q = 0; q < 2; q++)
                wv[q][kk] = W2[(size_t)(k4 * 4 + kk) * 64 + tx + 32 * q];
        #pragma unroll
        for (int nn = 0; nn < 8; nn++) {
            const float4 xv = *(const float4*)(xrow + nn * 128 + k4 * 4);
            #pragma unroll
            for (int q = 0; q < 2; q++)
                acc[q][nn] = fmaf(xv.x, wv[q][0], fmaf(xv.y, wv[q][1],
                             fmaf(xv.z, wv[q][2], fmaf(xv.w, wv[q][3], acc[q][nn]))));
        }
    }

    const float a0 = al2[tx], a1 = al2[tx + 32];
    const float r0 = ar2[tx], r1 = ar2[tx + 32];
    #pragma unroll
    for (int nn = 0; nn < 8; nn++) {
        const int n = n0 + ty * 8 + nn;
        const bool ok = (n < NN);
        if (ok) {
            h2h[(size_t)n * 64 + tx] = __float2half(acc[0][nn]);
            h2h[(size_t)n * 64 + tx + 32] = __float2half(acc[1][nn]);
        }
        float pe = acc[0][nn] * a0 + acc[1][nn] * a1;
        float pr = acc[0][nn] * r0 + acc[1][nn] * r1;
        #pragma unroll
        for (int m = 1; m < 32; m <<= 1) {
            pe += __shfl_xor(pe, m, 64);
            pr += __shfl_xor(pr, m, 64);
        }
        if (ok && tx == 0) { el2[n] = pe; er2[n] = pr; }
    }
}

// ---------------- Layer 2 aggregation: one wave per dst node ----------------
__global__ __launch_bounds__(128) void agg2_k(const int* __restrict__ offs,
                                              const int2* __restrict__ csr,
                                              const __half* __restrict__ h2h,
                                              const float* __restrict__ el2,
                                              const float* __restrict__ er2,
                                              const float* __restrict__ b2,
                                              float* __restrict__ out) {
    const int t = threadIdx.x, w = t >> 6, l = t & 63;
    const int n = blockIdx.x * 2 + w;
    const int beg = offs[n], deg = offs[n + 1] - beg;
    __shared__ int   lsrc[2][16];
    __shared__ float lw[2][16];
    __shared__ float pw[2][16];
    const int g = l & 7, es = l >> 3;
    const int e = l & 15;
    const float erd = er2[n];
    float m_run = -1e30f, z_run = 0.f;
    float acc[8];
    #pragma unroll
    for (int j = 0; j < 8; j++) acc[j] = 0.f;
    const float4* hp4 = (const float4*)h2h;

    for (int base = 0; base < deg; base += 16) {
        if (l < 16) {
            int2 pr = (base + l < deg) ? csr[beg + base + l] : make_int2(0, 0);
            lsrc[w][l] = pr.x;
            lw[w][l] = __int_as_float(pr.y);
        }
        asm volatile("" ::: "memory");
        float lg = -1e30f;
        if (base + e < deg) {
            const float v = el2[lsrc[w][e]] + erd;
            lg = v > 0.f ? v : 0.2f * v;
        }
        float tm = lg;
        tm = fmaxf(tm, __shfl_xor(tm, 1, 64));
        tm = fmaxf(tm, __shfl_xor(tm, 2, 64));
        tm = fmaxf(tm, __shfl_xor(tm, 4, 64));
        tm = fmaxf(tm, __shfl_xor(tm, 8, 64));
        const float m_new = fmaxf(m_run, tm);
        const float sc = __expf(m_run - m_new);
        const float p = __expf(lg - m_new);
        float za = p;
        za += __shfl_xor(za, 1, 64);
        za += __shfl_xor(za, 2, 64);
        za += __shfl_xor(za, 4, 64);
        za += __shfl_xor(za, 8, 64);
        z_run = z_run * sc + za;
        m_run = m_new;
        if (l < 16) pw[w][l] = p * lw[w][l];
        asm volatile("" ::: "memory");
        #pragma unroll
        for (int j = 0; j < 8; j++) acc[j] *= sc;
        const int sA = lsrc[w][es], sB = lsrc[w][es + 8];
        const float pA = pw[w][es], pB = pw[w][es + 8];
        const float4 vA = hp4[(size_t)sA * 8 + g];
        const float4 vB = hp4[(size_t)sB * 8 + g];
        #pragma unroll
        for (int q = 0; q < 4; q++) {
            const __half2 hA = ((const __half2*)&vA)[q];
            const __half2 hB = ((const __half2*)&vB)[q];
            const float2 fA = __half22float2(hA), fB = __half22float2(hB);
            acc[2 * q]     = fmaf(pA, fA.x, fmaf(pB, fB.x, acc[2 * q]));
            acc[2 * q + 1] = fmaf(pA, fA.y, fmaf(pB, fB.y, acc[2 * q + 1]));
        }
        asm volatile("" ::: "memory");
    }
    #pragma unroll
    for (int j = 0; j < 8; j++) {
        acc[j] += __shfl_xor(acc[j], 8, 64);
        acc[j] += __shfl_xor(acc[j], 16, 64);
        acc[j] += __shfl_xor(acc[j], 32, 64);
    }
    if (l < 8) {
        const float inv = (deg > 0) ? 1.f / z_run : 0.f;
        const float4* b4 = (const float4*)b2;
        const float4 bb0 = b4[g * 2], bb1 = b4[g * 2 + 1];
        float4 o0, o1;
        o0.x = acc[0] * inv + bb0.x;
        o0.y = acc[1] * inv + bb0.y;
        o0.z = acc[2] * inv + bb0.z;
        o0.w = acc[3] * inv + bb0.w;
        o1.x = acc[4] * inv + bb1.x;
        o1.y = acc[5] * inv + bb1.y;
        o1.z = acc[6] * inv + bb1.z;
        o1.w = acc[7] * inv + bb1.w;
        float4* op = (float4*)(out + (size_t)n * 64 + g * 8);
        op[0] = o0; op[1] = o1;
    }
}

// ---------------- host ----------------

extern "C" void kernel_launch(void* const* d_in, const int* in_sizes, int n_in,
                              void* d_out, int out_size, void* d_ws, size_t ws_size,
                              hipStream_t stream) {
    const float* feat = (const float*)d_in[0];
    const int*   srcv = (const int*)d_in[1];
    const int*   dstv = (const int*)d_in[2];
    const float* wE   = (const float*)d_in[3];
    const float* W1   = (const float*)d_in[4];
    const float* al1  = (const float*)d_in[5];
    const float* ar1  = (const float*)d_in[6];
    const float* b1   = (const float*)d_in[7];
    const float* W2   = (const float*)d_in[8];
    const float* al2  = (const float*)d_in[9];
    const float* ar2  = (const float*)d_in[10];
    const float* b2   = (const float*)d_in[11];
    float* out = (float*)d_out;

    char* ws = (char*)d_ws;
    size_t off = 0;
    auto take = [&](size_t bytes) -> char* {
        char* pp = ws + off;
        off = (off + bytes + 255) & ~(size_t)255;
        return pp;
    };
    __half* h1h = (__half*)take((size_t)NN * 128 * 2);
    __half* h2h = (__half*)take((size_t)NN * 64 * 2);
    float* h2in = (float*)take((size_t)NN * 128 * 4);   // 25.6 MB; first 8 MB aliased as sort staging
    float* el1  = (float*)take((size_t)NN * 8 * 4);
    float* er1  = (float*)take((size_t)NN * 8 * 4);
    float* el2  = (float*)take((size_t)NN * 4);
    float* er2  = (float*)take((size_t)NN * 4);
    int* counts = (int*)take((size_t)NN * 4);
    int* offs   = (int*)take((size_t)(NN + 1) * 4);
    int2* csr   = (int2*)take((size_t)NE * 8);
    int* bsum   = (int*)take((size_t)NB_C * 4);
    int* boff   = (int*)take((size_t)NB_C * 4);
    int* gcur   = (int*)take((size_t)NB * 4);
    int2* stage = (int2*)h2in;   // 128*8192*8 = 8 MB, used only before agg1 writes h2in

    init_counts_k<<<NB_C, 256, 0, stream>>>(counts, gcur);
    hist_k<<<(NE + 255) / 256, 256, 0, stream>>>(dstv, counts);
    partial_k<<<NB_C, 256, 0, stream>>>(counts, bsum);
    scanb_k<<<1, 256, 0, stream>>>(bsum, boff, offs + NN);
    offs_k<<<NB_C, 256, 0, stream>>>(counts, boff, offs);
    sortA_k<<<NBLK_A, 256, 0, stream>>>(srcv, dstv, wE, gcur, stage);
    sortB_k<<<NB, 256, 0, stream>>>(gcur, stage, offs, csr);
    proj1_k<<<(NN + 63) / 64, 256, 0, stream>>>(feat, W1, al1, ar1, h1h, el1, er1);
    agg1_k<<<NN / 2, 128, 0, stream>>>(offs, csr, h1h, el1, er1, b1, h2in);
    proj2_k<<<(NN + 63) / 64, 256, 0, stream>>>(h2in, W2, al2, ar2, h2h, el2, er2);
    agg2_k<<<NN / 2, 128, 0, stream>>>(offs, csr, h2h, el2, er2, b2, out);
}

// Round 5
// 223.225 us; speedup vs baseline: 1.1463x; 1.1463x over previous
//
#include <hip/hip_runtime.h>
#include <hip/hip_fp16.h>

#define NN 50000
#define NE 800000
#define NB_C ((NN + 255) / 256)   // 196 chunks of 256

// bucket sort params
#define NB 128
#define BRANGE 391                 // ceil(NN/NB), NB*BRANGE = 50048 >= NN
#define SCAP 8192                  // staging capacity per bucket
#define CHUNK 6144                 // edges per sortA block
#define NBLK_A ((NE + CHUNK - 1) / CHUNK)

typedef _Float16 f16x8 __attribute__((ext_vector_type(8)));
typedef float f32x4 __attribute__((ext_vector_type(4)));

// ---------------- CSR build ----------------

__global__ __launch_bounds__(256) void init_counts_k(int* counts, int* gcur) {
    int i = blockIdx.x * 256 + threadIdx.x;
    if (i < NN) counts[i] = 0;
    if (i < NB) gcur[i] = 0;
}

__global__ __launch_bounds__(256) void hist_k(const int* __restrict__ dst, int* __restrict__ counts) {
    int e = blockIdx.x * 256 + threadIdx.x;
    if (e < NE) atomicAdd(&counts[dst[e]], 1);
}

__global__ __launch_bounds__(256) void partial_k(const int* __restrict__ counts, int* __restrict__ bsum) {
    __shared__ int ws[4];
    const int t = threadIdx.x, i = blockIdx.x * 256 + t;
    int s = (i < NN) ? counts[i] : 0;
    #pragma unroll
    for (int m = 1; m < 64; m <<= 1) s += __shfl_xor(s, m, 64);
    if ((t & 63) == 0) ws[t >> 6] = s;
    __syncthreads();
    if (t == 0) bsum[blockIdx.x] = ws[0] + ws[1] + ws[2] + ws[3];
}

__global__ __launch_bounds__(256) void scanb_k(const int* __restrict__ bsum,
                                               int* __restrict__ boff,
                                               int* __restrict__ offs_last) {
    __shared__ int wsum[4];
    const int t = threadIdx.x, lane = t & 63, wid = t >> 6;
    const int v = (t < NB_C) ? bsum[t] : 0;
    int s = v;
    #pragma unroll
    for (int off = 1; off < 64; off <<= 1) {
        int tv = __shfl_up(s, off, 64);
        if (lane >= off) s += tv;
    }
    if (lane == 63) wsum[wid] = s;
    __syncthreads();
    int add = 0;
    for (int w = 0; w < wid; w++) add += wsum[w];
    const int excl = s - v + add;
    if (t < NB_C) boff[t] = excl;
    if (t == NB_C - 1) offs_last[0] = excl + v;
}

__global__ __launch_bounds__(256) void offs_k(const int* __restrict__ counts,
                                              const int* __restrict__ boff,
                                              int* __restrict__ offs) {
    __shared__ int wsum[4];
    const int t = threadIdx.x, lane = t & 63, wid = t >> 6;
    const int i = blockIdx.x * 256 + t;
    const int v = (i < NN) ? counts[i] : 0;
    int s = v;
    #pragma unroll
    for (int off = 1; off < 64; off <<= 1) {
        int tv = __shfl_up(s, off, 64);
        if (lane >= off) s += tv;
    }
    if (lane == 63) wsum[wid] = s;
    __syncthreads();
    int add = boff[blockIdx.x];
    for (int w = 0; w < wid; w++) add += wsum[w];
    const int excl = s - v + add;
    if (i < NN) offs[i] = excl;
}

// ---- sort pass A: bin edges into bucket-contiguous staging
__global__ __launch_bounds__(256) void sortA_k(const int* __restrict__ src,
                                               const int* __restrict__ dst,
                                               const float* __restrict__ wE,
                                               int* __restrict__ gcur,
                                               int2* __restrict__ stage) {
    __shared__ int hcnt[NB], lexcl[NB], lcur[NB], gbase[NB];
    __shared__ int2 lbuf[CHUNK];
    const int t = threadIdx.x;
    const int e0 = blockIdx.x * CHUNK;
    const int ne = min(CHUNK, NE - e0);
    for (int i = t; i < NB; i += 256) { hcnt[i] = 0; lcur[i] = 0; }
    __syncthreads();
    for (int i = t; i < ne; i += 256) {
        const int b = dst[e0 + i] / BRANGE;
        atomicAdd(&hcnt[b], 1);
    }
    __syncthreads();
    if (t < 64) {
        const int v0 = hcnt[2 * t], v1 = hcnt[2 * t + 1];
        const int s = v0 + v1;
        int inc = s;
        #pragma unroll
        for (int off = 1; off < 64; off <<= 1) {
            int u = __shfl_up(inc, off, 64);
            if (t >= off) inc += u;
        }
        const int excl = inc - s;
        lexcl[2 * t] = excl;
        lexcl[2 * t + 1] = excl + v0;
    }
    __syncthreads();
    if (t < NB && hcnt[t] > 0) gbase[t] = atomicAdd(&gcur[t], hcnt[t]);
    __syncthreads();
    for (int i = t; i < ne; i += 256) {
        const int d = dst[e0 + i];
        const int b = d / BRANGE;
        const int r = atomicAdd(&lcur[b], 1);
        const int dloc = d - b * BRANGE;
        lbuf[lexcl[b] + r] = make_int2(src[e0 + i] | (dloc << 16), __float_as_int(wE[e0 + i]));
    }
    __syncthreads();
    for (int b = 0; b < NB; b++) {
        const int cnt = hcnt[b], lo = lexcl[b];
        int2* dp = stage + (size_t)b * SCAP + gbase[b];
        for (int j = t; j < cnt; j += 256) dp[j] = lbuf[lo + j];
    }
}

// ---- sort pass B: one block per bucket
__global__ __launch_bounds__(256) void sortB_k(const int* __restrict__ gcur,
                                               const int2* __restrict__ stage,
                                               const int* __restrict__ offs,
                                               int2* __restrict__ csr) {
    __shared__ int lcur[BRANGE];
    const int b = blockIdx.x, t = threadIdx.x;
    for (int i = t; i < BRANGE; i += 256) lcur[i] = 0;
    __syncthreads();
    const int nb = gcur[b];
    const int dlo = b * BRANGE;
    const int2* sp = stage + (size_t)b * SCAP;
    for (int i = t; i < nb; i += 256) {
        const int2 pr = sp[i];
        const int dloc = (pr.x >> 16) & 0x1FF;
        const int sv = pr.x & 0xFFFF;
        const int r = atomicAdd(&lcur[dloc], 1);
        csr[offs[dlo + dloc] + r] = make_int2(sv, pr.y);
    }
}

// ---- convert + transpose weights to fp16 (w1t[n][k], w2t[n][k])
__global__ __launch_bounds__(256) void convw_k(const float* __restrict__ W1,
                                               const float* __restrict__ W2,
                                               __half* __restrict__ w1t,
                                               __half* __restrict__ w2t) {
    int i = blockIdx.x * 256 + threadIdx.x;
    if (i < 128 * 128) {
        const int k = i >> 7, n = i & 127;
        w1t[(size_t)n * 128 + k] = __float2half(W1[i]);
    }
    if (i < 128 * 64) {
        const int k = i >> 6, n = i & 63;
        w2t[(size_t)n * 128 + k] = __float2half(W2[i]);
    }
}

// ---------------- Layer 1 projection (MFMA): h1h = x @ W1, el1/er1 fused ----------------
// 256 threads = 4 waves; wave computes rows [rbase, rbase+16) x 128 cols.
__global__ __launch_bounds__(256) void proj1_k(const float* __restrict__ x,
                                               const __half* __restrict__ w1t,
                                               const float* __restrict__ al1,
                                               const float* __restrict__ ar1,
                                               __half* __restrict__ h1h,
                                               float* __restrict__ el1,
                                               float* __restrict__ er1) {
    const int t = threadIdx.x, l = t & 63, wv = t >> 6;
    const int rbase = blockIdx.x * 64 + wv * 16;
    const int cl = l & 15, kg = l >> 4;
    const int arow = rbase + cl;
    const float* xrow = x + (size_t)(arow < NN ? arow : NN - 1) * 128;
    f16x8 afrag[4];
    #pragma unroll
    for (int ks = 0; ks < 4; ks++) {
        const float4 u0 = *(const float4*)(xrow + ks * 32 + kg * 8);
        const float4 u1 = *(const float4*)(xrow + ks * 32 + kg * 8 + 4);
        f16x8 a;
        a[0] = (_Float16)u0.x; a[1] = (_Float16)u0.y; a[2] = (_Float16)u0.z; a[3] = (_Float16)u0.w;
        a[4] = (_Float16)u1.x; a[5] = (_Float16)u1.y; a[6] = (_Float16)u1.z; a[7] = (_Float16)u1.w;
        afrag[ks] = a;
    }
    f32x4 acc[8];
    #pragma unroll
    for (int nt = 0; nt < 8; nt++) { acc[nt][0]=0.f; acc[nt][1]=0.f; acc[nt][2]=0.f; acc[nt][3]=0.f; }
    #pragma unroll
    for (int nt = 0; nt < 8; nt++) {
        const f16x8* bp = (const f16x8*)(w1t + (size_t)(nt * 16 + cl) * 128 + kg * 8);
        #pragma unroll
        for (int ks = 0; ks < 4; ks++)
            acc[nt] = __builtin_amdgcn_mfma_f32_16x16x32_f16(afrag[ks], bp[ks * 4], acc[nt], 0, 0, 0);
    }
    const int orow0 = rbase + kg * 4;
    #pragma unroll
    for (int nt = 0; nt < 8; nt++) {
        const int col = nt * 16 + cl;
        const float alc = al1[col], arc = ar1[col];
        #pragma unroll
        for (int r = 0; r < 4; r++) {
            const float v = acc[nt][r];
            const int orow = orow0 + r;
            const bool ok = (orow < NN);
            if (ok) h1h[(size_t)orow * 128 + col] = __float2half(v);
            float pe = v * alc, pr = v * arc;
            #pragma unroll
            for (int m = 1; m < 16; m <<= 1) {
                pe += __shfl_xor(pe, m, 64);
                pr += __shfl_xor(pr, m, 64);
            }
            if (ok && cl == 0) {
                el1[(size_t)orow * 8 + nt] = pe;
                er1[(size_t)orow * 8 + nt] = pr;
            }
        }
    }
}

// ---------------- Layer 1 aggregation: one wave per dst node ----------------
__global__ __launch_bounds__(128) void agg1_k(const int* __restrict__ offs,
                                              const int2* __restrict__ csr,
                                              const __half* __restrict__ h1h,
                                              const float* __restrict__ el1,
                                              const float* __restrict__ er1,
                                              const float* __restrict__ b1,
                                              __half* __restrict__ h2in_h) {
    const int t = threadIdx.x, w = t >> 6, l = t & 63;
    const int n = blockIdx.x * 2 + w;
    const int beg = offs[n], deg = offs[n + 1] - beg;
    __shared__ int   lsrc[2][16];
    __shared__ float lw[2][16];
    __shared__ float pw[2][128];
    const int h = l & 7, g = l & 15, es = l >> 4, hg = g >> 1;
    const int e0 = l >> 3, e1 = e0 + 8;
    const float er_h = er1[(size_t)n * 8 + h];
    float m_run = -1e30f, z_run = 0.f;
    float acc[8];
    #pragma unroll
    for (int j = 0; j < 8; j++) acc[j] = 0.f;
    const float4* hp4 = (const float4*)h1h;

    for (int base = 0; base < deg; base += 16) {
        if (l < 16) {
            int2 pr = (base + l < deg) ? csr[beg + base + l] : make_int2(0, 0);
            lsrc[w][l] = pr.x;
            lw[w][l] = __int_as_float(pr.y);
        }
        asm volatile("" ::: "memory");
        float lg0 = -1e30f, lg1 = -1e30f;
        if (base + e0 < deg) {
            const float v = el1[(size_t)lsrc[w][e0] * 8 + h] + er_h;
            lg0 = v > 0.f ? v : 0.2f * v;
        }
        if (base + e1 < deg) {
            const float v = el1[(size_t)lsrc[w][e1] * 8 + h] + er_h;
            lg1 = v > 0.f ? v : 0.2f * v;
        }
        float tm = fmaxf(lg0, lg1);
        tm = fmaxf(tm, __shfl_xor(tm, 8, 64));
        tm = fmaxf(tm, __shfl_xor(tm, 16, 64));
        tm = fmaxf(tm, __shfl_xor(tm, 32, 64));
        const float m_new = fmaxf(m_run, tm);
        const float sc = __expf(m_run - m_new);
        const float p0 = __expf(lg0 - m_new);
        const float p1 = __expf(lg1 - m_new);
        float za = p0 + p1;
        za += __shfl_xor(za, 8, 64);
        za += __shfl_xor(za, 16, 64);
        za += __shfl_xor(za, 32, 64);
        z_run = z_run * sc + za;
        m_run = m_new;
        pw[w][l] = p0 * lw[w][e0];
        pw[w][l + 64] = p1 * lw[w][e1];
        asm volatile("" ::: "memory");
        const float scg = __shfl(sc, hg, 8);
        #pragma unroll
        for (int j = 0; j < 8; j++) acc[j] *= scg;
        const int sA = lsrc[w][es], sB = lsrc[w][es + 4], sC = lsrc[w][es + 8], sD = lsrc[w][es + 12];
        const float pA = pw[w][es * 8 + hg], pB = pw[w][(es + 4) * 8 + hg];
        const float pC = pw[w][(es + 8) * 8 + hg], pD = pw[w][(es + 12) * 8 + hg];
        const float4 vA = hp4[(size_t)sA * 16 + g];
        const float4 vB = hp4[(size_t)sB * 16 + g];
        const float4 vC = hp4[(size_t)sC * 16 + g];
        const float4 vD = hp4[(size_t)sD * 16 + g];
        #pragma unroll
        for (int q = 0; q < 4; q++) {
            const __half2 hA = ((const __half2*)&vA)[q];
            const __half2 hB = ((const __half2*)&vB)[q];
            const __half2 hC = ((const __half2*)&vC)[q];
            const __half2 hD = ((const __half2*)&vD)[q];
            const float2 fA = __half22float2(hA), fB = __half22float2(hB);
            const float2 fC = __half22float2(hC), fD = __half22float2(hD);
            acc[2 * q]     = fmaf(pA, fA.x, fmaf(pB, fB.x, fmaf(pC, fC.x, fmaf(pD, fD.x, acc[2 * q]))));
            acc[2 * q + 1] = fmaf(pA, fA.y, fmaf(pB, fB.y, fmaf(pC, fC.y, fmaf(pD, fD.y, acc[2 * q + 1]))));
        }
        asm volatile("" ::: "memory");
    }
    #pragma unroll
    for (int j = 0; j < 8; j++) {
        acc[j] += __shfl_xor(acc[j], 16, 64);
        acc[j] += __shfl_xor(acc[j], 32, 64);
    }
    const float zg = __shfl(z_run, hg, 8);
    if (l < 16) {
        const float inv = (deg > 0) ? 1.f / zg : 0.f;
        const float4* b4 = (const float4*)b1;
        const float4 bb0 = b4[g * 2], bb1 = b4[g * 2 + 1];
        __half hv[8];
        hv[0] = __float2half(fmaxf(acc[0] * inv + bb0.x, 0.f));
        hv[1] = __float2half(fmaxf(acc[1] * inv + bb0.y, 0.f));
        hv[2] = __float2half(fmaxf(acc[2] * inv + bb0.z, 0.f));
        hv[3] = __float2half(fmaxf(acc[3] * inv + bb0.w, 0.f));
        hv[4] = __float2half(fmaxf(acc[4] * inv + bb1.x, 0.f));
        hv[5] = __float2half(fmaxf(acc[5] * inv + bb1.y, 0.f));
        hv[6] = __float2half(fmaxf(acc[6] * inv + bb1.z, 0.f));
        hv[7] = __float2half(fmaxf(acc[7] * inv + bb1.w, 0.f));
        *(int4*)(h2in_h + (size_t)n * 128 + g * 8) = *(const int4*)hv;
    }
}

// ---------------- Layer 2 projection (MFMA): h2h = h2in_h @ W2, el2/er2 fused ----------------
__global__ __launch_bounds__(256) void proj2_k(const __half* __restrict__ xh,
                                               const __half* __restrict__ w2t,
                                               const float* __restrict__ al2,
                                               const float* __restrict__ ar2,
                                               __half* __restrict__ h2h,
                                               float* __restrict__ el2,
                                               float* __restrict__ er2) {
    const int t = threadIdx.x, l = t & 63, wv = t >> 6;
    const int rbase = blockIdx.x * 64 + wv * 16;
    const int cl = l & 15, kg = l >> 4;
    const int arow = rbase + cl;
    const __half* xrow = xh + (size_t)(arow < NN ? arow : NN - 1) * 128;
    f16x8 afrag[4];
    #pragma unroll
    for (int ks = 0; ks < 4; ks++)
        afrag[ks] = *(const f16x8*)(xrow + ks * 32 + kg * 8);
    f32x4 acc[4];
    #pragma unroll
    for (int nt = 0; nt < 4; nt++) { acc[nt][0]=0.f; acc[nt][1]=0.f; acc[nt][2]=0.f; acc[nt][3]=0.f; }
    #pragma unroll
    for (int nt = 0; nt < 4; nt++) {
        const f16x8* bp = (const f16x8*)(w2t + (size_t)(nt * 16 + cl) * 128 + kg * 8);
        #pragma unroll
        for (int ks = 0; ks < 4; ks++)
            acc[nt] = __builtin_amdgcn_mfma_f32_16x16x32_f16(afrag[ks], bp[ks * 4], acc[nt], 0, 0, 0);
    }
    const int orow0 = rbase + kg * 4;
    float pe[4] = {0.f, 0.f, 0.f, 0.f}, pr[4] = {0.f, 0.f, 0.f, 0.f};
    #pragma unroll
    for (int nt = 0; nt < 4; nt++) {
        const int col = nt * 16 + cl;
        const float alc = al2[col], arc = ar2[col];
        #pragma unroll
        for (int r = 0; r < 4; r++) {
            const float v = acc[nt][r];
            const int orow = orow0 + r;
            if (orow < NN) h2h[(size_t)orow * 64 + col] = __float2half(v);
            pe[r] = fmaf(v, alc, pe[r]);
            pr[r] = fmaf(v, arc, pr[r]);
        }
    }
    #pragma unroll
    for (int r = 0; r < 4; r++) {
        #pragma unroll
        for (int m = 1; m < 16; m <<= 1) {
            pe[r] += __shfl_xor(pe[r], m, 64);
            pr[r] += __shfl_xor(pr[r], m, 64);
        }
        const int orow = orow0 + r;
        if (cl == 0 && orow < NN) { el2[orow] = pe[r]; er2[orow] = pr[r]; }
    }
}

// ---------------- Layer 2 aggregation: one wave per dst node ----------------
__global__ __launch_bounds__(128) void agg2_k(const int* __restrict__ offs,
                                              const int2* __restrict__ csr,
                                              const __half* __restrict__ h2h,
                                              const float* __restrict__ el2,
                                              const float* __restrict__ er2,
                                              const float* __restrict__ b2,
                                              float* __restrict__ out) {
    const int t = threadIdx.x, w = t >> 6, l = t & 63;
    const int n = blockIdx.x * 2 + w;
    const int beg = offs[n], deg = offs[n + 1] - beg;
    __shared__ int   lsrc[2][16];
    __shared__ float lw[2][16];
    __shared__ float pw[2][16];
    const int g = l & 7, es = l >> 3;
    const int e = l & 15;
    const float erd = er2[n];
    float m_run = -1e30f, z_run = 0.f;
    float acc[8];
    #pragma unroll
    for (int j = 0; j < 8; j++) acc[j] = 0.f;
    const float4* hp4 = (const float4*)h2h;

    for (int base = 0; base < deg; base += 16) {
        if (l < 16) {
            int2 pr = (base + l < deg) ? csr[beg + base + l] : make_int2(0, 0);
            lsrc[w][l] = pr.x;
            lw[w][l] = __int_as_float(pr.y);
        }
        asm volatile("" ::: "memory");
        float lg = -1e30f;
        if (base + e < deg) {
            const float v = el2[lsrc[w][e]] + erd;
            lg = v > 0.f ? v : 0.2f * v;
        }
        float tm = lg;
        tm = fmaxf(tm, __shfl_xor(tm, 1, 64));
        tm = fmaxf(tm, __shfl_xor(tm, 2, 64));
        tm = fmaxf(tm, __shfl_xor(tm, 4, 64));
        tm = fmaxf(tm, __shfl_xor(tm, 8, 64));
        const float m_new = fmaxf(m_run, tm);
        const float sc = __expf(m_run - m_new);
        const float p = __expf(lg - m_new);
        float za = p;
        za += __shfl_xor(za, 1, 64);
        za += __shfl_xor(za, 2, 64);
        za += __shfl_xor(za, 4, 64);
        za += __shfl_xor(za, 8, 64);
        z_run = z_run * sc + za;
        m_run = m_new;
        if (l < 16) pw[w][l] = p * lw[w][l];
        asm volatile("" ::: "memory");
        #pragma unroll
        for (int j = 0; j < 8; j++) acc[j] *= sc;
        const int sA = lsrc[w][es], sB = lsrc[w][es + 8];
        const float pA = pw[w][es], pB = pw[w][es + 8];
        const float4 vA = hp4[(size_t)sA * 8 + g];
        const float4 vB = hp4[(size_t)sB * 8 + g];
        #pragma unroll
        for (int q = 0; q < 4; q++) {
            const __half2 hA = ((const __half2*)&vA)[q];
            const __half2 hB = ((const __half2*)&vB)[q];
            const float2 fA = __half22float2(hA), fB = __half22float2(hB);
            acc[2 * q]     = fmaf(pA, fA.x, fmaf(pB, fB.x, acc[2 * q]));
            acc[2 * q + 1] = fmaf(pA, fA.y, fmaf(pB, fB.y, acc[2 * q + 1]));
        }
        asm volatile("" ::: "memory");
    }
    #pragma unroll
    for (int j = 0; j < 8; j++) {
        acc[j] += __shfl_xor(acc[j], 8, 64);
        acc[j] += __shfl_xor(acc[j], 16, 64);
        acc[j] += __shfl_xor(acc[j], 32, 64);
    }
    if (l < 8) {
        const float inv = (deg > 0) ? 1.f / z_run : 0.f;
        const float4* b4 = (const float4*)b2;
        const float4 bb0 = b4[g * 2], bb1 = b4[g * 2 + 1];
        float4 o0, o1;
        o0.x = acc[0] * inv + bb0.x;
        o0.y = acc[1] * inv + bb0.y;
        o0.z = acc[2] * inv + bb0.z;
        o0.w = acc[3] * inv + bb0.w;
        o1.x = acc[4] * inv + bb1.x;
        o1.y = acc[5] * inv + bb1.y;
        o1.z = acc[6] * inv + bb1.z;
        o1.w = acc[7] * inv + bb1.w;
        float4* op = (float4*)(out + (size_t)n * 64 + g * 8);
        op[0] = o0; op[1] = o1;
    }
}

// ---------------- host ----------------

extern "C" void kernel_launch(void* const* d_in, const int* in_sizes, int n_in,
                              void* d_out, int out_size, void* d_ws, size_t ws_size,
                              hipStream_t stream) {
    const float* feat = (const float*)d_in[0];
    const int*   srcv = (const int*)d_in[1];
    const int*   dstv = (const int*)d_in[2];
    const float* wE   = (const float*)d_in[3];
    const float* W1   = (const float*)d_in[4];
    const float* al1  = (const float*)d_in[5];
    const float* ar1  = (const float*)d_in[6];
    const float* b1   = (const float*)d_in[7];
    const float* W2   = (const float*)d_in[8];
    const float* al2  = (const float*)d_in[9];
    const float* ar2  = (const float*)d_in[10];
    const float* b2   = (const float*)d_in[11];
    float* out = (float*)d_out;

    char* ws = (char*)d_ws;
    size_t off = 0;
    auto take = [&](size_t bytes) -> char* {
        char* pp = ws + off;
        off = (off + bytes + 255) & ~(size_t)255;
        return pp;
    };
    __half* h1h   = (__half*)take((size_t)NN * 128 * 2);
    __half* h2h   = (__half*)take((size_t)NN * 64 * 2);
    __half* h2in_h= (__half*)take((size_t)NN * 128 * 2);   // 12.8 MB; first 8 MB aliased as sort staging
    float* el1  = (float*)take((size_t)NN * 8 * 4);
    float* er1  = (float*)take((size_t)NN * 8 * 4);
    float* el2  = (float*)take((size_t)NN * 4);
    float* er2  = (float*)take((size_t)NN * 4);
    int* counts = (int*)take((size_t)NN * 4);
    int* offs   = (int*)take((size_t)(NN + 1) * 4);
    int2* csr   = (int2*)take((size_t)NE * 8);
    int* bsum   = (int*)take((size_t)NB_C * 4);
    int* boff   = (int*)take((size_t)NB_C * 4);
    int* gcur   = (int*)take((size_t)NB * 4);
    __half* w1t = (__half*)take((size_t)128 * 128 * 2);
    __half* w2t = (__half*)take((size_t)64 * 128 * 2);
    int2* stage = (int2*)h2in_h;   // 128*8192*8 = 8 MB, consumed before agg1 writes h2in_h

    convw_k<<<64, 256, 0, stream>>>(W1, W2, w1t, w2t);
    init_counts_k<<<NB_C, 256, 0, stream>>>(counts, gcur);
    hist_k<<<(NE + 255) / 256, 256, 0, stream>>>(dstv, counts);
    partial_k<<<NB_C, 256, 0, stream>>>(counts, bsum);
    scanb_k<<<1, 256, 0, stream>>>(bsum, boff, offs + NN);
    offs_k<<<NB_C, 256, 0, stream>>>(counts, boff, offs);
    sortA_k<<<NBLK_A, 256, 0, stream>>>(srcv, dstv, wE, gcur, stage);
    sortB_k<<<NB, 256, 0, stream>>>(gcur, stage, offs, csr);
    proj1_k<<<(NN + 63) / 64, 256, 0, stream>>>(feat, w1t, al1, ar1, h1h, el1, er1);
    agg1_k<<<NN / 2, 128, 0, stream>>>(offs, csr, h1h, el1, er1, b1, h2in_h);
    proj2_k<<<(NN + 63) / 64, 256, 0, stream>>>(h2in_h, w2t, al2, ar2, h2h, el2, er2);
    agg2_k<<<NN / 2, 128, 0, stream>>>(offs, csr, h2h, el2, er2, b2, out);
}

// Round 6
// 216.546 us; speedup vs baseline: 1.1817x; 1.0308x over previous
//
#include <hip/hip_runtime.h>
#include <hip/hip_fp16.h>

#define NN 50000
#define NE 800000
#define NB_C ((NN + 255) / 256)   // 196 chunks of 256

// bucket sort params
#define NB 128
#define BRANGE 391                 // ceil(NN/NB), NB*BRANGE = 50048 >= NN
#define SCAP 8192                  // staging capacity per bucket
#define CHUNK 6144                 // edges per sortA block
#define NBLK_A ((NE + CHUNK - 1) / CHUNK)

typedef _Float16 f16x8 __attribute__((ext_vector_type(8)));
typedef float f32x4 __attribute__((ext_vector_type(4)));

// ---------------- CSR build ----------------

__global__ __launch_bounds__(256) void init_counts_k(int* counts, int* gcur) {
    int i = blockIdx.x * 256 + threadIdx.x;
    if (i < NN) counts[i] = 0;
    if (i < NB) gcur[i] = 0;
}

__global__ __launch_bounds__(256) void hist_k(const int* __restrict__ dst, int* __restrict__ counts) {
    int e = blockIdx.x * 256 + threadIdx.x;
    if (e < NE) atomicAdd(&counts[dst[e]], 1);
}

__global__ __launch_bounds__(256) void partial_k(const int* __restrict__ counts, int* __restrict__ bsum) {
    __shared__ int ws[4];
    const int t = threadIdx.x, i = blockIdx.x * 256 + t;
    int s = (i < NN) ? counts[i] : 0;
    #pragma unroll
    for (int m = 1; m < 64; m <<= 1) s += __shfl_xor(s, m, 64);
    if ((t & 63) == 0) ws[t >> 6] = s;
    __syncthreads();
    if (t == 0) bsum[blockIdx.x] = ws[0] + ws[1] + ws[2] + ws[3];
}

__global__ __launch_bounds__(256) void scanb_k(const int* __restrict__ bsum,
                                               int* __restrict__ boff,
                                               int* __restrict__ offs_last) {
    __shared__ int wsum[4];
    const int t = threadIdx.x, lane = t & 63, wid = t >> 6;
    const int v = (t < NB_C) ? bsum[t] : 0;
    int s = v;
    #pragma unroll
    for (int off = 1; off < 64; off <<= 1) {
        int tv = __shfl_up(s, off, 64);
        if (lane >= off) s += tv;
    }
    if (lane == 63) wsum[wid] = s;
    __syncthreads();
    int add = 0;
    for (int w = 0; w < wid; w++) add += wsum[w];
    const int excl = s - v + add;
    if (t < NB_C) boff[t] = excl;
    if (t == NB_C - 1) offs_last[0] = excl + v;
}

__global__ __launch_bounds__(256) void offs_k(const int* __restrict__ counts,
                                              const int* __restrict__ boff,
                                              int* __restrict__ offs) {
    __shared__ int wsum[4];
    const int t = threadIdx.x, lane = t & 63, wid = t >> 6;
    const int i = blockIdx.x * 256 + t;
    const int v = (i < NN) ? counts[i] : 0;
    int s = v;
    #pragma unroll
    for (int off = 1; off < 64; off <<= 1) {
        int tv = __shfl_up(s, off, 64);
        if (lane >= off) s += tv;
    }
    if (lane == 63) wsum[wid] = s;
    __syncthreads();
    int add = boff[blockIdx.x];
    for (int w = 0; w < wid; w++) add += wsum[w];
    const int excl = s - v + add;
    if (i < NN) offs[i] = excl;
}

// ---- sort pass A: bin edges into bucket-contiguous staging
__global__ __launch_bounds__(256) void sortA_k(const int* __restrict__ src,
                                               const int* __restrict__ dst,
                                               const float* __restrict__ wE,
                                               int* __restrict__ gcur,
                                               int2* __restrict__ stage) {
    __shared__ int hcnt[NB], lexcl[NB], lcur[NB], gbase[NB];
    __shared__ int2 lbuf[CHUNK];
    const int t = threadIdx.x;
    const int e0 = blockIdx.x * CHUNK;
    const int ne = min(CHUNK, NE - e0);
    for (int i = t; i < NB; i += 256) { hcnt[i] = 0; lcur[i] = 0; }
    __syncthreads();
    for (int i = t; i < ne; i += 256) {
        const int b = dst[e0 + i] / BRANGE;
        atomicAdd(&hcnt[b], 1);
    }
    __syncthreads();
    if (t < 64) {
        const int v0 = hcnt[2 * t], v1 = hcnt[2 * t + 1];
        const int s = v0 + v1;
        int inc = s;
        #pragma unroll
        for (int off = 1; off < 64; off <<= 1) {
            int u = __shfl_up(inc, off, 64);
            if (t >= off) inc += u;
        }
        const int excl = inc - s;
        lexcl[2 * t] = excl;
        lexcl[2 * t + 1] = excl + v0;
    }
    __syncthreads();
    if (t < NB && hcnt[t] > 0) gbase[t] = atomicAdd(&gcur[t], hcnt[t]);
    __syncthreads();
    for (int i = t; i < ne; i += 256) {
        const int d = dst[e0 + i];
        const int b = d / BRANGE;
        const int r = atomicAdd(&lcur[b], 1);
        const int dloc = d - b * BRANGE;
        lbuf[lexcl[b] + r] = make_int2(src[e0 + i] | (dloc << 16), __float_as_int(wE[e0 + i]));
    }
    __syncthreads();
    for (int b = 0; b < NB; b++) {
        const int cnt = hcnt[b], lo = lexcl[b];
        int2* dp = stage + (size_t)b * SCAP + gbase[b];
        for (int j = t; j < cnt; j += 256) dp[j] = lbuf[lo + j];
    }
}

// ---- sort pass B: one block per bucket
__global__ __launch_bounds__(256) void sortB_k(const int* __restrict__ gcur,
                                               const int2* __restrict__ stage,
                                               const int* __restrict__ offs,
                                               int2* __restrict__ csr) {
    __shared__ int lcur[BRANGE];
    const int b = blockIdx.x, t = threadIdx.x;
    for (int i = t; i < BRANGE; i += 256) lcur[i] = 0;
    __syncthreads();
    const int nb = gcur[b];
    const int dlo = b * BRANGE;
    const int2* sp = stage + (size_t)b * SCAP;
    for (int i = t; i < nb; i += 256) {
        const int2 pr = sp[i];
        const int dloc = (pr.x >> 16) & 0x1FF;
        const int sv = pr.x & 0xFFFF;
        const int r = atomicAdd(&lcur[dloc], 1);
        csr[offs[dlo + dloc] + r] = make_int2(sv, pr.y);
    }
}

// ---- convert + transpose weights to fp16 (w1t[n][k], w2t[n][k])
__global__ __launch_bounds__(256) void convw_k(const float* __restrict__ W1,
                                               const float* __restrict__ W2,
                                               __half* __restrict__ w1t,
                                               __half* __restrict__ w2t) {
    int i = blockIdx.x * 256 + threadIdx.x;
    if (i < 128 * 128) {
        const int k = i >> 7, n = i & 127;
        w1t[(size_t)n * 128 + k] = __float2half(W1[i]);
    }
    if (i < 128 * 64) {
        const int k = i >> 6, n = i & 63;
        w2t[(size_t)n * 128 + k] = __float2half(W2[i]);
    }
}

// ---------------- Layer 1 projection (MFMA) ----------------
__global__ __launch_bounds__(256) void proj1_k(const float* __restrict__ x,
                                               const __half* __restrict__ w1t,
                                               const float* __restrict__ al1,
                                               const float* __restrict__ ar1,
                                               __half* __restrict__ h1h,
                                               float* __restrict__ el1,
                                               float* __restrict__ er1) {
    const int t = threadIdx.x, l = t & 63, wv = t >> 6;
    const int rbase = blockIdx.x * 64 + wv * 16;
    const int cl = l & 15, kg = l >> 4;
    const int arow = rbase + cl;
    const float* xrow = x + (size_t)(arow < NN ? arow : NN - 1) * 128;
    f16x8 afrag[4];
    #pragma unroll
    for (int ks = 0; ks < 4; ks++) {
        const float4 u0 = *(const float4*)(xrow + ks * 32 + kg * 8);
        const float4 u1 = *(const float4*)(xrow + ks * 32 + kg * 8 + 4);
        f16x8 a;
        a[0] = (_Float16)u0.x; a[1] = (_Float16)u0.y; a[2] = (_Float16)u0.z; a[3] = (_Float16)u0.w;
        a[4] = (_Float16)u1.x; a[5] = (_Float16)u1.y; a[6] = (_Float16)u1.z; a[7] = (_Float16)u1.w;
        afrag[ks] = a;
    }
    f32x4 acc[8];
    #pragma unroll
    for (int nt = 0; nt < 8; nt++) { acc[nt][0]=0.f; acc[nt][1]=0.f; acc[nt][2]=0.f; acc[nt][3]=0.f; }
    #pragma unroll
    for (int nt = 0; nt < 8; nt++) {
        const f16x8* bp = (const f16x8*)(w1t + (size_t)(nt * 16 + cl) * 128 + kg * 8);
        #pragma unroll
        for (int ks = 0; ks < 4; ks++)
            acc[nt] = __builtin_amdgcn_mfma_f32_16x16x32_f16(afrag[ks], bp[ks * 4], acc[nt], 0, 0, 0);
    }
    const int orow0 = rbase + kg * 4;
    #pragma unroll
    for (int nt = 0; nt < 8; nt++) {
        const int col = nt * 16 + cl;
        const float alc = al1[col], arc = ar1[col];
        #pragma unroll
        for (int r = 0; r < 4; r++) {
            const float v = acc[nt][r];
            const int orow = orow0 + r;
            const bool ok = (orow < NN);
            if (ok) h1h[(size_t)orow * 128 + col] = __float2half(v);
            float pe = v * alc, pr = v * arc;
            #pragma unroll
            for (int m = 1; m < 16; m <<= 1) {
                pe += __shfl_xor(pe, m, 64);
                pr += __shfl_xor(pr, m, 64);
            }
            if (ok && cl == 0) {
                el1[(size_t)orow * 8 + nt] = pe;
                er1[(size_t)orow * 8 + nt] = pr;
            }
        }
    }
}

// ---------------- Layer 1 aggregation: one wave per dst node, flat-exp softmax, all-shfl ----------------
// Lane roles: logits: head h=l&7, edges e0=l>>3, e1=e0+8. values: g=l&15 (dims 8g..), es=l>>4, head hg=g>>1.
__global__ __launch_bounds__(128) void agg1_k(const int* __restrict__ offs,
                                              const int2* __restrict__ csr,
                                              const __half* __restrict__ h1h,
                                              const float* __restrict__ el1,
                                              const float* __restrict__ er1,
                                              const float* __restrict__ b1,
                                              __half* __restrict__ h2in_h) {
    const int t = threadIdx.x, w = t >> 6, l = t & 63;
    const int n = blockIdx.x * 2 + w;
    const int beg = offs[n], deg = offs[n + 1] - beg;
    const int h = l & 7, g = l & 15, es = l >> 4, hg = g >> 1;
    const int e0 = l >> 3, e1 = e0 + 8;
    const float er_h = er1[(size_t)n * 8 + h];
    float z_lane = 0.f;
    float acc[8];
    #pragma unroll
    for (int j = 0; j < 8; j++) acc[j] = 0.f;
    const float4* hp4 = (const float4*)h1h;

    for (int base = 0; base < deg; base += 16) {
        int2 pr = make_int2(0, 0);
        if (l < 16 && base + l < deg) pr = csr[beg + base + l];
        const float wv = __int_as_float(pr.y);
        // logits for edges e0, e1 at head h
        const int se0 = __shfl(pr.x, e0, 64);
        const int se1 = __shfl(pr.x, e1, 64);
        float lg0 = -1e30f, lg1 = -1e30f;
        if (base + e0 < deg) {
            const float v = el1[(size_t)se0 * 8 + h] + er_h;
            lg0 = v > 0.f ? v : 0.2f * v;
        }
        if (base + e1 < deg) {
            const float v = el1[(size_t)se1 * 8 + h] + er_h;
            lg1 = v > 0.f ? v : 0.2f * v;
        }
        const float p0 = __expf(lg0);      // 0 for padded slots
        const float p1 = __expf(lg1);
        z_lane += p0 + p1;
        const float w0 = __shfl(wv, e0, 64), w1 = __shfl(wv, e1, 64);
        const float pw0 = p0 * w0, pw1 = p1 * w1;
        // values: edges es, es+4, es+8, es+12 at head hg
        const int sA = __shfl(pr.x, es, 64), sB = __shfl(pr.x, es + 4, 64);
        const int sC = __shfl(pr.x, es + 8, 64), sD = __shfl(pr.x, es + 12, 64);
        const float pA = __shfl(pw0, es * 8 + hg, 64), pB = __shfl(pw0, (es + 4) * 8 + hg, 64);
        const float pC = __shfl(pw1, es * 8 + hg, 64), pD = __shfl(pw1, (es + 4) * 8 + hg, 64);
        const float4 vA = hp4[(size_t)sA * 16 + g];
        const float4 vB = hp4[(size_t)sB * 16 + g];
        const float4 vC = hp4[(size_t)sC * 16 + g];
        const float4 vD = hp4[(size_t)sD * 16 + g];
        #pragma unroll
        for (int q = 0; q < 4; q++) {
            const float2 fA = __half22float2(((const __half2*)&vA)[q]);
            const float2 fB = __half22float2(((const __half2*)&vB)[q]);
            const float2 fC = __half22float2(((const __half2*)&vC)[q]);
            const float2 fD = __half22float2(((const __half2*)&vD)[q]);
            acc[2 * q]     = fmaf(pA, fA.x, fmaf(pB, fB.x, fmaf(pC, fC.x, fmaf(pD, fD.x, acc[2 * q]))));
            acc[2 * q + 1] = fmaf(pA, fA.y, fmaf(pB, fB.y, fmaf(pC, fC.y, fmaf(pD, fD.y, acc[2 * q + 1]))));
        }
    }
    // z: reduce over e8 lanes (bits 3,4,5) -> lane (0,h8) pattern; every lane gets z[its h]
    z_lane += __shfl_xor(z_lane, 8, 64);
    z_lane += __shfl_xor(z_lane, 16, 64);
    z_lane += __shfl_xor(z_lane, 32, 64);
    // acc: reduce over es (bits 4,5)
    #pragma unroll
    for (int j = 0; j < 8; j++) {
        acc[j] += __shfl_xor(acc[j], 16, 64);
        acc[j] += __shfl_xor(acc[j], 32, 64);
    }
    const float zg = __shfl(z_lane, hg, 64);   // z for head hg (from lane hg)
    if (l < 16) {
        const float inv = (deg > 0) ? 1.f / zg : 0.f;
        const float4* b4 = (const float4*)b1;
        const float4 bb0 = b4[g * 2], bb1 = b4[g * 2 + 1];
        __half hv[8];
        hv[0] = __float2half(fmaxf(acc[0] * inv + bb0.x, 0.f));
        hv[1] = __float2half(fmaxf(acc[1] * inv + bb0.y, 0.f));
        hv[2] = __float2half(fmaxf(acc[2] * inv + bb0.z, 0.f));
        hv[3] = __float2half(fmaxf(acc[3] * inv + bb0.w, 0.f));
        hv[4] = __float2half(fmaxf(acc[4] * inv + bb1.x, 0.f));
        hv[5] = __float2half(fmaxf(acc[5] * inv + bb1.y, 0.f));
        hv[6] = __float2half(fmaxf(acc[6] * inv + bb1.z, 0.f));
        hv[7] = __float2half(fmaxf(acc[7] * inv + bb1.w, 0.f));
        *(int4*)(h2in_h + (size_t)n * 128 + g * 8) = *(const int4*)hv;
    }
}

// ---------------- Layer 2 projection (MFMA) ----------------
__global__ __launch_bounds__(256) void proj2_k(const __half* __restrict__ xh,
                                               const __half* __restrict__ w2t,
                                               const float* __restrict__ al2,
                                               const float* __restrict__ ar2,
                                               __half* __restrict__ h2h,
                                               float* __restrict__ el2,
                                               float* __restrict__ er2) {
    const int t = threadIdx.x, l = t & 63, wv = t >> 6;
    const int rbase = blockIdx.x * 64 + wv * 16;
    const int cl = l & 15, kg = l >> 4;
    const int arow = rbase + cl;
    const __half* xrow = xh + (size_t)(arow < NN ? arow : NN - 1) * 128;
    f16x8 afrag[4];
    #pragma unroll
    for (int ks = 0; ks < 4; ks++)
        afrag[ks] = *(const f16x8*)(xrow + ks * 32 + kg * 8);
    f32x4 acc[4];
    #pragma unroll
    for (int nt = 0; nt < 4; nt++) { acc[nt][0]=0.f; acc[nt][1]=0.f; acc[nt][2]=0.f; acc[nt][3]=0.f; }
    #pragma unroll
    for (int nt = 0; nt < 4; nt++) {
        const f16x8* bp = (const f16x8*)(w2t + (size_t)(nt * 16 + cl) * 128 + kg * 8);
        #pragma unroll
        for (int ks = 0; ks < 4; ks++)
            acc[nt] = __builtin_amdgcn_mfma_f32_16x16x32_f16(afrag[ks], bp[ks * 4], acc[nt], 0, 0, 0);
    }
    const int orow0 = rbase + kg * 4;
    float pe[4] = {0.f, 0.f, 0.f, 0.f}, pr[4] = {0.f, 0.f, 0.f, 0.f};
    #pragma unroll
    for (int nt = 0; nt < 4; nt++) {
        const int col = nt * 16 + cl;
        const float alc = al2[col], arc = ar2[col];
        #pragma unroll
        for (int r = 0; r < 4; r++) {
            const float v = acc[nt][r];
            const int orow = orow0 + r;
            if (orow < NN) h2h[(size_t)orow * 64 + col] = __float2half(v);
            pe[r] = fmaf(v, alc, pe[r]);
            pr[r] = fmaf(v, arc, pr[r]);
        }
    }
    #pragma unroll
    for (int r = 0; r < 4; r++) {
        #pragma unroll
        for (int m = 1; m < 16; m <<= 1) {
            pe[r] += __shfl_xor(pe[r], m, 64);
            pr[r] += __shfl_xor(pr[r], m, 64);
        }
        const int orow = orow0 + r;
        if (cl == 0 && orow < NN) { el2[orow] = pe[r]; er2[orow] = pr[r]; }
    }
}

// ---------------- Layer 2 aggregation: one wave per dst node, flat-exp, all-shfl ----------------
// Lane roles: logits: edge e=l&15 (4x redundant). values: g=l&7 (dim group), es=l>>3 (edges es, es+8).
__global__ __launch_bounds__(128) void agg2_k(const int* __restrict__ offs,
                                              const int2* __restrict__ csr,
                                              const __half* __restrict__ h2h,
                                              const float* __restrict__ el2,
                                              const float* __restrict__ er2,
                                              const float* __restrict__ b2,
                                              float* __restrict__ out) {
    const int t = threadIdx.x, w = t >> 6, l = t & 63;
    const int n = blockIdx.x * 2 + w;
    const int beg = offs[n], deg = offs[n + 1] - beg;
    const int g = l & 7, es = l >> 3;
    const int e = l & 15;
    const float erd = er2[n];
    float z_lane = 0.f;
    float acc[8];
    #pragma unroll
    for (int j = 0; j < 8; j++) acc[j] = 0.f;
    const float4* hp4 = (const float4*)h2h;

    for (int base = 0; base < deg; base += 16) {
        int2 pr = make_int2(0, 0);
        if (l < 16 && base + l < deg) pr = csr[beg + base + l];
        const float wv = __int_as_float(pr.y);
        const int se = __shfl(pr.x, e, 64);
        float lg = -1e30f;
        if (base + e < deg) {
            const float v = el2[se] + erd;
            lg = v > 0.f ? v : 0.2f * v;
        }
        const float p = __expf(lg);        // 0 for padded slots
        z_lane += p;                       // each 16-lane group sums all 16 edges once
        const float pw = p * __shfl(wv, e, 64);
        const int sA = __shfl(pr.x, es, 64), sB = __shfl(pr.x, es + 8, 64);
        const float pA = __shfl(pw, es, 64), pB = __shfl(pw, es + 8, 64);
        const float4 vA = hp4[(size_t)sA * 8 + g];
        const float4 vB = hp4[(size_t)sB * 8 + g];
        #pragma unroll
        for (int q = 0; q < 4; q++) {
            const float2 fA = __half22float2(((const __half2*)&vA)[q]);
            const float2 fB = __half22float2(((const __half2*)&vB)[q]);
            acc[2 * q]     = fmaf(pA, fA.x, fmaf(pB, fB.x, acc[2 * q]));
            acc[2 * q + 1] = fmaf(pA, fA.y, fmaf(pB, fB.y, acc[2 * q + 1]));
        }
    }
    // z: reduce within 16-lane groups (bits 0-3)
    z_lane += __shfl_xor(z_lane, 1, 64);
    z_lane += __shfl_xor(z_lane, 2, 64);
    z_lane += __shfl_xor(z_lane, 4, 64);
    z_lane += __shfl_xor(z_lane, 8, 64);
    // acc: reduce over es (bits 3,4,5)
    #pragma unroll
    for (int j = 0; j < 8; j++) {
        acc[j] += __shfl_xor(acc[j], 8, 64);
        acc[j] += __shfl_xor(acc[j], 16, 64);
        acc[j] += __shfl_xor(acc[j], 32, 64);
    }
    if (l < 8) {
        const float inv = (deg > 0) ? 1.f / z_lane : 0.f;
        const float4* b4 = (const float4*)b2;
        const float4 bb0 = b4[g * 2], bb1 = b4[g * 2 + 1];
        float4 o0, o1;
        o0.x = acc[0] * inv + bb0.x;
        o0.y = acc[1] * inv + bb0.y;
        o0.z = acc[2] * inv + bb0.z;
        o0.w = acc[3] * inv + bb0.w;
        o1.x = acc[4] * inv + bb1.x;
        o1.y = acc[5] * inv + bb1.y;
        o1.z = acc[6] * inv + bb1.z;
        o1.w = acc[7] * inv + bb1.w;
        float4* op = (float4*)(out + (size_t)n * 64 + g * 8);
        op[0] = o0; op[1] = o1;
    }
}

// ---------------- host ----------------

extern "C" void kernel_launch(void* const* d_in, const int* in_sizes, int n_in,
                              void* d_out, int out_size, void* d_ws, size_t ws_size,
                              hipStream_t stream) {
    const float* feat = (const float*)d_in[0];
    const int*   srcv = (const int*)d_in[1];
    const int*   dstv = (const int*)d_in[2];
    const float* wE   = (const float*)d_in[3];
    const float* W1   = (const float*)d_in[4];
    const float* al1  = (const float*)d_in[5];
    const float* ar1  = (const float*)d_in[6];
    const float* b1   = (const float*)d_in[7];
    const float* W2   = (const float*)d_in[8];
    const float* al2  = (const float*)d_in[9];
    const float* ar2  = (const float*)d_in[10];
    const float* b2   = (const float*)d_in[11];
    float* out = (float*)d_out;

    char* ws = (char*)d_ws;
    size_t off = 0;
    auto take = [&](size_t bytes) -> char* {
        char* pp = ws + off;
        off = (off + bytes + 255) & ~(size_t)255;
        return pp;
    };
    __half* h1h   = (__half*)take((size_t)NN * 128 * 2);
    __half* h2h   = (__half*)take((size_t)NN * 64 * 2);
    __half* h2in_h= (__half*)take((size_t)NN * 128 * 2);   // 12.8 MB; first 8 MB aliased as sort staging
    float* el1  = (float*)take((size_t)NN * 8 * 4);
    float* er1  = (float*)take((size_t)NN * 8 * 4);
    float* el2  = (float*)take((size_t)NN * 4);
    float* er2  = (float*)take((size_t)NN * 4);
    int* counts = (int*)take((size_t)NN * 4);
    int* offs   = (int*)take((size_t)(NN + 1) * 4);
    int2* csr   = (int2*)take((size_t)NE * 8);
    int* bsum   = (int*)take((size_t)NB_C * 4);
    int* boff   = (int*)take((size_t)NB_C * 4);
    int* gcur   = (int*)take((size_t)NB * 4);
    __half* w1t = (__half*)take((size_t)128 * 128 * 2);
    __half* w2t = (__half*)take((size_t)64 * 128 * 2);
    int2* stage = (int2*)h2in_h;   // 8 MB, consumed before agg1 writes h2in_h

    convw_k<<<64, 256, 0, stream>>>(W1, W2, w1t, w2t);
    init_counts_k<<<NB_C, 256, 0, stream>>>(counts, gcur);
    hist_k<<<(NE + 255) / 256, 256, 0, stream>>>(dstv, counts);
    partial_k<<<NB_C, 256, 0, stream>>>(counts, bsum);
    scanb_k<<<1, 256, 0, stream>>>(bsum, boff, offs + NN);
    offs_k<<<NB_C, 256, 0, stream>>>(counts, boff, offs);
    sortA_k<<<NBLK_A, 256, 0, stream>>>(srcv, dstv, wE, gcur, stage);
    sortB_k<<<NB, 256, 0, stream>>>(gcur, stage, offs, csr);
    proj1_k<<<(NN + 63) / 64, 256, 0, stream>>>(feat, w1t, al1, ar1, h1h, el1, er1);
    agg1_k<<<NN / 2, 128, 0, stream>>>(offs, csr, h1h, el1, er1, b1, h2in_h);
    proj2_k<<<(NN + 63) / 64, 256, 0, stream>>>(h2in_h, w2t, al2, ar2, h2h, el2, er2);
    agg2_k<<<NN / 2, 128, 0, stream>>>(offs, csr, h2h, el2, er2, b2, out);
}

// Round 7
// 160.920 us; speedup vs baseline: 1.5902x; 1.3457x over previous
//
#include <hip/hip_runtime.h>
#include <hip/hip_fp16.h>

#define NN 50000
#define NE 800000

// bucket sort: bucket = dst >> 8 (256 dsts per bucket)
#define NBK 196                    // ceil(50000/256)
#define BSH 8
#define BMASK 255
#define SCAP 5120                  // >= max bucket population (mean 4082)
#define CHUNK 1024                 // edges per sortA block
#define NBLK_A ((NE + CHUNK - 1) / CHUNK)

typedef _Float16 f16x8 __attribute__((ext_vector_type(8)));
typedef float f32x4 __attribute__((ext_vector_type(4)));

// ---------------- CSR build ----------------

__global__ __launch_bounds__(256) void initg_k(int* gcur) {
    if (threadIdx.x < NBK) gcur[threadIdx.x] = 0;
}

// pass A: bin edges into bucket-contiguous staging. 1024 edges/block, wave-parallel flush.
__global__ __launch_bounds__(256) void sortA_k(const int* __restrict__ src,
                                               const int* __restrict__ dst,
                                               const float* __restrict__ wE,
                                               int* __restrict__ gcur,
                                               int2* __restrict__ stage) {
    __shared__ int hcnt[NBK], lexcl[NBK], lcur[NBK], gbase[NBK];
    __shared__ int wsum[4];
    __shared__ int2 lbuf[CHUNK];
    const int t = threadIdx.x;
    const int e0 = blockIdx.x * CHUNK;
    const int ne = min(CHUNK, NE - e0);
    if (t < NBK) { hcnt[t] = 0; lcur[t] = 0; }
    __syncthreads();
    for (int i = t; i < ne; i += 256) atomicAdd(&hcnt[dst[e0 + i] >> BSH], 1);
    __syncthreads();
    {   // exclusive scan of hcnt[0..NBK) across 256 threads
        const int lane = t & 63, wid = t >> 6;
        const int v = (t < NBK) ? hcnt[t] : 0;
        int s = v;
        #pragma unroll
        for (int off = 1; off < 64; off <<= 1) {
            int u = __shfl_up(s, off, 64);
            if (lane >= off) s += u;
        }
        if (lane == 63) wsum[wid] = s;
        __syncthreads();
        int add = 0;
        for (int w = 0; w < wid; w++) add += wsum[w];
        if (t < NBK) lexcl[t] = s - v + add;
    }
    __syncthreads();
    if (t < NBK && hcnt[t] > 0) gbase[t] = atomicAdd(&gcur[t], hcnt[t]);
    __syncthreads();
    for (int i = t; i < ne; i += 256) {
        const int d = dst[e0 + i];
        const int b = d >> BSH;
        const int r = atomicAdd(&lcur[b], 1);
        lbuf[lexcl[b] + r] = make_int2((src[e0 + i] & 0xFFFF) | ((d & BMASK) << 16),
                                       __float_as_int(wE[e0 + i]));
    }
    __syncthreads();
    const int wv = t >> 6, lane = t & 63;
    for (int b = wv; b < NBK; b += 4) {
        const int cnt = hcnt[b];
        if (cnt == 0) continue;
        const int lo = lexcl[b];
        int2* dp = stage + (size_t)b * SCAP + gbase[b];
        for (int j = lane; j < cnt; j += 64) dp[j] = lbuf[lo + j];
    }
}

// scan the 196 bucket totals -> bucket bases in csr; also offs[NN]=NE
__global__ __launch_bounds__(256) void scang_k(const int* __restrict__ gcur,
                                               int* __restrict__ gb2,
                                               int* __restrict__ offs_last) {
    __shared__ int wsum[4];
    const int t = threadIdx.x, lane = t & 63, wid = t >> 6;
    const int v = (t < NBK) ? gcur[t] : 0;
    int s = v;
    #pragma unroll
    for (int off = 1; off < 64; off <<= 1) {
        int u = __shfl_up(s, off, 64);
        if (lane >= off) s += u;
    }
    if (lane == 63) wsum[wid] = s;
    __syncthreads();
    int add = 0;
    for (int w = 0; w < wid; w++) add += wsum[w];
    if (t < NBK) gb2[t] = s - v + add;
    if (t == 0) offs_last[0] = NE;
}

// pass B: per bucket: local dst-histogram -> offs[] for its range, then scatter to final csr (u32 payload)
__global__ __launch_bounds__(512) void sortB_k(const int* __restrict__ gcur,
                                               const int* __restrict__ gb2,
                                               const int2* __restrict__ stage,
                                               int* __restrict__ offs,
                                               unsigned int* __restrict__ csr) {
    __shared__ int cnt[256], cur[256];
    __shared__ int wsum[8];
    const int b = blockIdx.x, t = threadIdx.x;
    const int nb = gcur[b];
    const int base = gb2[b];
    const int dlo = b << BSH;
    if (t < 256) cnt[t] = 0;
    __syncthreads();
    const int2* sp = stage + (size_t)b * SCAP;
    for (int i = t; i < nb; i += 512) atomicAdd(&cnt[(sp[i].x >> 16) & BMASK], 1);
    __syncthreads();
    {   // exclusive scan of cnt[0..256) across 512 threads (upper half zeros)
        const int lane = t & 63, wid = t >> 6;
        const int v = (t < 256) ? cnt[t] : 0;
        int s = v;
        #pragma unroll
        for (int off = 1; off < 64; off <<= 1) {
            int u = __shfl_up(s, off, 64);
            if (lane >= off) s += u;
        }
        if (lane == 63) wsum[wid] = s;
        __syncthreads();
        int add = 0;
        for (int w = 0; w < wid; w++) add += wsum[w];
        const int excl = s - v + add;
        if (t < 256) {
            cur[t] = excl;
            if (dlo + t < NN) offs[dlo + t] = base + excl;
        }
        if (t == 0) offs[min(dlo + 256, NN)] = base + nb;
    }
    __syncthreads();
    for (int i = t; i < nb; i += 512) {
        const int2 pr = sp[i];
        const int dloc = (pr.x >> 16) & BMASK;
        const int sv = pr.x & 0xFFFF;
        const int r = atomicAdd(&cur[dloc], 1);
        const __half hw = __float2half(__int_as_float(pr.y));
        csr[base + r] = (unsigned int)sv | ((unsigned int)__half_as_ushort(hw) << 16);
    }
}

// ---- convert + transpose weights to fp16 (w1t[n][k], w2t[n][k])
__global__ __launch_bounds__(256) void convw_k(const float* __restrict__ W1,
                                               const float* __restrict__ W2,
                                               __half* __restrict__ w1t,
                                               __half* __restrict__ w2t) {
    int i = blockIdx.x * 256 + threadIdx.x;
    if (i < 128 * 128) {
        const int k = i >> 7, n = i & 127;
        w1t[(size_t)n * 128 + k] = __float2half(W1[i]);
    }
    if (i < 128 * 64) {
        const int k = i >> 6, n = i & 63;
        w2t[(size_t)n * 128 + k] = __float2half(W2[i]);
    }
}

// ---------------- Layer 1 projection (MFMA) ----------------
__global__ __launch_bounds__(256) void proj1_k(const float* __restrict__ x,
                                               const __half* __restrict__ w1t,
                                               const float* __restrict__ al1,
                                               const float* __restrict__ ar1,
                                               __half* __restrict__ h1h,
                                               float* __restrict__ el1,
                                               float* __restrict__ er1) {
    const int t = threadIdx.x, l = t & 63, wv = t >> 6;
    const int rbase = blockIdx.x * 64 + wv * 16;
    const int cl = l & 15, kg = l >> 4;
    const int arow = rbase + cl;
    const float* xrow = x + (size_t)(arow < NN ? arow : NN - 1) * 128;
    f16x8 afrag[4];
    #pragma unroll
    for (int ks = 0; ks < 4; ks++) {
        const float4 u0 = *(const float4*)(xrow + ks * 32 + kg * 8);
        const float4 u1 = *(const float4*)(xrow + ks * 32 + kg * 8 + 4);
        f16x8 a;
        a[0] = (_Float16)u0.x; a[1] = (_Float16)u0.y; a[2] = (_Float16)u0.z; a[3] = (_Float16)u0.w;
        a[4] = (_Float16)u1.x; a[5] = (_Float16)u1.y; a[6] = (_Float16)u1.z; a[7] = (_Float16)u1.w;
        afrag[ks] = a;
    }
    f32x4 acc[8];
    #pragma unroll
    for (int nt = 0; nt < 8; nt++) { acc[nt][0]=0.f; acc[nt][1]=0.f; acc[nt][2]=0.f; acc[nt][3]=0.f; }
    #pragma unroll
    for (int nt = 0; nt < 8; nt++) {
        const f16x8* bp = (const f16x8*)(w1t + (size_t)(nt * 16 + cl) * 128 + kg * 8);
        #pragma unroll
        for (int ks = 0; ks < 4; ks++)
            acc[nt] = __builtin_amdgcn_mfma_f32_16x16x32_f16(afrag[ks], bp[ks * 4], acc[nt], 0, 0, 0);
    }
    const int orow0 = rbase + kg * 4;
    #pragma unroll
    for (int nt = 0; nt < 8; nt++) {
        const int col = nt * 16 + cl;
        const float alc = al1[col], arc = ar1[col];
        #pragma unroll
        for (int r = 0; r < 4; r++) {
            const float v = acc[nt][r];
            const int orow = orow0 + r;
            const bool ok = (orow < NN);
            if (ok) h1h[(size_t)orow * 128 + col] = __float2half(v);
            float pe = v * alc, pr = v * arc;
            #pragma unroll
            for (int m = 1; m < 16; m <<= 1) {
                pe += __shfl_xor(pe, m, 64);
                pr += __shfl_xor(pr, m, 64);
            }
            if (ok && cl == 0) {
                el1[(size_t)orow * 8 + nt] = pe;
                er1[(size_t)orow * 8 + nt] = pr;
            }
        }
    }
}

// ---------------- Layer 1 aggregation: one wave per dst node, flat-exp, all-shfl ----------------
__global__ __launch_bounds__(128) void agg1_k(const int* __restrict__ offs,
                                              const unsigned int* __restrict__ csr,
                                              const __half* __restrict__ h1h,
                                              const float* __restrict__ el1,
                                              const float* __restrict__ er1,
                                              const float* __restrict__ b1,
                                              __half* __restrict__ h2in_h) {
    const int t = threadIdx.x, w = t >> 6, l = t & 63;
    const int n = blockIdx.x * 2 + w;
    const int beg = offs[n], deg = offs[n + 1] - beg;
    const int h = l & 7, g = l & 15, es = l >> 4, hg = g >> 1;
    const int e0 = l >> 3, e1 = e0 + 8;
    const float er_h = er1[(size_t)n * 8 + h];
    float z_lane = 0.f;
    float acc[8];
    #pragma unroll
    for (int j = 0; j < 8; j++) acc[j] = 0.f;
    const float4* hp4 = (const float4*)h1h;

    for (int base = 0; base < deg; base += 16) {
        int pr = 0;
        if (l < 16 && base + l < deg) pr = (int)csr[beg + base + l];
        const unsigned int pr0 = (unsigned int)__shfl(pr, e0, 64);
        const unsigned int pr1 = (unsigned int)__shfl(pr, e1, 64);
        float lg0 = -1e30f, lg1 = -1e30f;
        if (base + e0 < deg) {
            const float v = el1[(size_t)(pr0 & 0xFFFF) * 8 + h] + er_h;
            lg0 = v > 0.f ? v : 0.2f * v;
        }
        if (base + e1 < deg) {
            const float v = el1[(size_t)(pr1 & 0xFFFF) * 8 + h] + er_h;
            lg1 = v > 0.f ? v : 0.2f * v;
        }
        const float p0 = __expf(lg0);      // 0 for padded slots
        const float p1 = __expf(lg1);
        z_lane += p0 + p1;
        const float w0 = __half2float(__ushort_as_half((unsigned short)(pr0 >> 16)));
        const float w1 = __half2float(__ushort_as_half((unsigned short)(pr1 >> 16)));
        const float pw0 = p0 * w0, pw1 = p1 * w1;
        const int sA = __shfl(pr, es, 64) & 0xFFFF, sB = __shfl(pr, es + 4, 64) & 0xFFFF;
        const int sC = __shfl(pr, es + 8, 64) & 0xFFFF, sD = __shfl(pr, es + 12, 64) & 0xFFFF;
        const float pA = __shfl(pw0, es * 8 + hg, 64), pB = __shfl(pw0, (es + 4) * 8 + hg, 64);
        const float pC = __shfl(pw1, es * 8 + hg, 64), pD = __shfl(pw1, (es + 4) * 8 + hg, 64);
        const float4 vA = hp4[(size_t)sA * 16 + g];
        const float4 vB = hp4[(size_t)sB * 16 + g];
        const float4 vC = hp4[(size_t)sC * 16 + g];
        const float4 vD = hp4[(size_t)sD * 16 + g];
        #pragma unroll
        for (int q = 0; q < 4; q++) {
            const float2 fA = __half22float2(((const __half2*)&vA)[q]);
            const float2 fB = __half22float2(((const __half2*)&vB)[q]);
            const float2 fC = __half22float2(((const __half2*)&vC)[q]);
            const float2 fD = __half22float2(((const __half2*)&vD)[q]);
            acc[2 * q]     = fmaf(pA, fA.x, fmaf(pB, fB.x, fmaf(pC, fC.x, fmaf(pD, fD.x, acc[2 * q]))));
            acc[2 * q + 1] = fmaf(pA, fA.y, fmaf(pB, fB.y, fmaf(pC, fC.y, fmaf(pD, fD.y, acc[2 * q + 1]))));
        }
    }
    z_lane += __shfl_xor(z_lane, 8, 64);
    z_lane += __shfl_xor(z_lane, 16, 64);
    z_lane += __shfl_xor(z_lane, 32, 64);
    #pragma unroll
    for (int j = 0; j < 8; j++) {
        acc[j] += __shfl_xor(acc[j], 16, 64);
        acc[j] += __shfl_xor(acc[j], 32, 64);
    }
    const float zg = __shfl(z_lane, hg, 64);
    if (l < 16) {
        const float inv = (deg > 0) ? 1.f / zg : 0.f;
        const float4* b4 = (const float4*)b1;
        const float4 bb0 = b4[g * 2], bb1 = b4[g * 2 + 1];
        __half hv[8];
        hv[0] = __float2half(fmaxf(acc[0] * inv + bb0.x, 0.f));
        hv[1] = __float2half(fmaxf(acc[1] * inv + bb0.y, 0.f));
        hv[2] = __float2half(fmaxf(acc[2] * inv + bb0.z, 0.f));
        hv[3] = __float2half(fmaxf(acc[3] * inv + bb0.w, 0.f));
        hv[4] = __float2half(fmaxf(acc[4] * inv + bb1.x, 0.f));
        hv[5] = __float2half(fmaxf(acc[5] * inv + bb1.y, 0.f));
        hv[6] = __float2half(fmaxf(acc[6] * inv + bb1.z, 0.f));
        hv[7] = __float2half(fmaxf(acc[7] * inv + bb1.w, 0.f));
        *(int4*)(h2in_h + (size_t)n * 128 + g * 8) = *(const int4*)hv;
    }
}

// ---------------- Layer 2 projection (MFMA) ----------------
__global__ __launch_bounds__(256) void proj2_k(const __half* __restrict__ xh,
                                               const __half* __restrict__ w2t,
                                               const float* __restrict__ al2,
                                               const float* __restrict__ ar2,
                                               __half* __restrict__ h2h,
                                               float* __restrict__ el2,
                                               float* __restrict__ er2) {
    const int t = threadIdx.x, l = t & 63, wv = t >> 6;
    const int rbase = blockIdx.x * 64 + wv * 16;
    const int cl = l & 15, kg = l >> 4;
    const int arow = rbase + cl;
    const __half* xrow = xh + (size_t)(arow < NN ? arow : NN - 1) * 128;
    f16x8 afrag[4];
    #pragma unroll
    for (int ks = 0; ks < 4; ks++)
        afrag[ks] = *(const f16x8*)(xrow + ks * 32 + kg * 8);
    f32x4 acc[4];
    #pragma unroll
    for (int nt = 0; nt < 4; nt++) { acc[nt][0]=0.f; acc[nt][1]=0.f; acc[nt][2]=0.f; acc[nt][3]=0.f; }
    #pragma unroll
    for (int nt = 0; nt < 4; nt++) {
        const f16x8* bp = (const f16x8*)(w2t + (size_t)(nt * 16 + cl) * 128 + kg * 8);
        #pragma unroll
        for (int ks = 0; ks < 4; ks++)
            acc[nt] = __builtin_amdgcn_mfma_f32_16x16x32_f16(afrag[ks], bp[ks * 4], acc[nt], 0, 0, 0);
    }
    const int orow0 = rbase + kg * 4;
    float pe[4] = {0.f, 0.f, 0.f, 0.f}, pr[4] = {0.f, 0.f, 0.f, 0.f};
    #pragma unroll
    for (int nt = 0; nt < 4; nt++) {
        const int col = nt * 16 + cl;
        const float alc = al2[col], arc = ar2[col];
        #pragma unroll
        for (int r = 0; r < 4; r++) {
            const float v = acc[nt][r];
            const int orow = orow0 + r;
            if (orow < NN) h2h[(size_t)orow * 64 + col] = __float2half(v);
            pe[r] = fmaf(v, alc, pe[r]);
            pr[r] = fmaf(v, arc, pr[r]);
        }
    }
    #pragma unroll
    for (int r = 0; r < 4; r++) {
        #pragma unroll
        for (int m = 1; m < 16; m <<= 1) {
            pe[r] += __shfl_xor(pe[r], m, 64);
            pr[r] += __shfl_xor(pr[r], m, 64);
        }
        const int orow = orow0 + r;
        if (cl == 0 && orow < NN) { el2[orow] = pe[r]; er2[orow] = pr[r]; }
    }
}

// ---------------- Layer 2 aggregation ----------------
__global__ __launch_bounds__(128) void agg2_k(const int* __restrict__ offs,
                                              const unsigned int* __restrict__ csr,
                                              const __half* __restrict__ h2h,
                                              const float* __restrict__ el2,
                                              const float* __restrict__ er2,
                                              const float* __restrict__ b2,
                                              float* __restrict__ out) {
    const int t = threadIdx.x, w = t >> 6, l = t & 63;
    const int n = blockIdx.x * 2 + w;
    const int beg = offs[n], deg = offs[n + 1] - beg;
    const int g = l & 7, es = l >> 3;
    const int e = l & 15;
    const float erd = er2[n];
    float z_lane = 0.f;
    float acc[8];
    #pragma unroll
    for (int j = 0; j < 8; j++) acc[j] = 0.f;
    const float4* hp4 = (const float4*)h2h;

    for (int base = 0; base < deg; base += 16) {
        int pr = 0;
        if (l < 16 && base + l < deg) pr = (int)csr[beg + base + l];
        const unsigned int prE = (unsigned int)__shfl(pr, e, 64);
        float lg = -1e30f;
        if (base + e < deg) {
            const float v = el2[prE & 0xFFFF] + erd;
            lg = v > 0.f ? v : 0.2f * v;
        }
        const float p = __expf(lg);
        z_lane += p;
        const float pw = p * __half2float(__ushort_as_half((unsigned short)(prE >> 16)));
        const int sA = __shfl(pr, es, 64) & 0xFFFF, sB = __shfl(pr, es + 8, 64) & 0xFFFF;
        const float pA = __shfl(pw, es, 64), pB = __shfl(pw, es + 8, 64);
        const float4 vA = hp4[(size_t)sA * 8 + g];
        const float4 vB = hp4[(size_t)sB * 8 + g];
        #pragma unroll
        for (int q = 0; q < 4; q++) {
            const float2 fA = __half22float2(((const __half2*)&vA)[q]);
            const float2 fB = __half22float2(((const __half2*)&vB)[q]);
            acc[2 * q]     = fmaf(pA, fA.x, fmaf(pB, fB.x, acc[2 * q]));
            acc[2 * q + 1] = fmaf(pA, fA.y, fmaf(pB, fB.y, acc[2 * q + 1]));
        }
    }
    z_lane += __shfl_xor(z_lane, 1, 64);
    z_lane += __shfl_xor(z_lane, 2, 64);
    z_lane += __shfl_xor(z_lane, 4, 64);
    z_lane += __shfl_xor(z_lane, 8, 64);
    #pragma unroll
    for (int j = 0; j < 8; j++) {
        acc[j] += __shfl_xor(acc[j], 8, 64);
        acc[j] += __shfl_xor(acc[j], 16, 64);
        acc[j] += __shfl_xor(acc[j], 32, 64);
    }
    if (l < 8) {
        const float inv = (deg > 0) ? 1.f / z_lane : 0.f;
        const float4* b4 = (const float4*)b2;
        const float4 bb0 = b4[g * 2], bb1 = b4[g * 2 + 1];
        float4 o0, o1;
        o0.x = acc[0] * inv + bb0.x;
        o0.y = acc[1] * inv + bb0.y;
        o0.z = acc[2] * inv + bb0.z;
        o0.w = acc[3] * inv + bb0.w;
        o1.x = acc[4] * inv + bb1.x;
        o1.y = acc[5] * inv + bb1.y;
        o1.z = acc[6] * inv + bb1.z;
        o1.w = acc[7] * inv + bb1.w;
        float4* op = (float4*)(out + (size_t)n * 64 + g * 8);
        op[0] = o0; op[1] = o1;
    }
}

// ---------------- host ----------------

extern "C" void kernel_launch(void* const* d_in, const int* in_sizes, int n_in,
                              void* d_out, int out_size, void* d_ws, size_t ws_size,
                              hipStream_t stream) {
    const float* feat = (const float*)d_in[0];
    const int*   srcv = (const int*)d_in[1];
    const int*   dstv = (const int*)d_in[2];
    const float* wE   = (const float*)d_in[3];
    const float* W1   = (const float*)d_in[4];
    const float* al1  = (const float*)d_in[5];
    const float* ar1  = (const float*)d_in[6];
    const float* b1   = (const float*)d_in[7];
    const float* W2   = (const float*)d_in[8];
    const float* al2  = (const float*)d_in[9];
    const float* ar2  = (const float*)d_in[10];
    const float* b2   = (const float*)d_in[11];
    float* out = (float*)d_out;

    char* ws = (char*)d_ws;
    size_t off = 0;
    auto take = [&](size_t bytes) -> char* {
        char* pp = ws + off;
        off = (off + bytes + 255) & ~(size_t)255;
        return pp;
    };
    __half* h1h   = (__half*)take((size_t)NN * 128 * 2);
    __half* h2h   = (__half*)take((size_t)NN * 64 * 2);
    __half* h2in_h= (__half*)take((size_t)NN * 128 * 2);   // 12.8 MB; first ~8 MB aliased as sort staging
    float* el1  = (float*)take((size_t)NN * 8 * 4);
    float* er1  = (float*)take((size_t)NN * 8 * 4);
    float* el2  = (float*)take((size_t)NN * 4);
    float* er2  = (float*)take((size_t)NN * 4);
    int* offs   = (int*)take((size_t)(NN + 1) * 4);
    unsigned int* csr = (unsigned int*)take((size_t)NE * 4);
    int* gcur   = (int*)take((size_t)NBK * 4);
    int* gb2    = (int*)take((size_t)NBK * 4);
    __half* w1t = (__half*)take((size_t)128 * 128 * 2);
    __half* w2t = (__half*)take((size_t)64 * 128 * 2);
    int2* stage = (int2*)h2in_h;   // NBK*SCAP*8 = 8.03 MB, consumed before agg1 writes h2in_h

    initg_k<<<1, 256, 0, stream>>>(gcur);
    sortA_k<<<NBLK_A, 256, 0, stream>>>(srcv, dstv, wE, gcur, stage);
    scang_k<<<1, 256, 0, stream>>>(gcur, gb2, offs + NN);
    sortB_k<<<NBK, 512, 0, stream>>>(gcur, gb2, stage, offs, csr);
    convw_k<<<64, 256, 0, stream>>>(W1, W2, w1t, w2t);
    proj1_k<<<(NN + 63) / 64, 256, 0, stream>>>(feat, w1t, al1, ar1, h1h, el1, er1);
    agg1_k<<<NN / 2, 128, 0, stream>>>(offs, csr, h1h, el1, er1, b1, h2in_h);
    proj2_k<<<(NN + 63) / 64, 256, 0, stream>>>(h2in_h, w2t, al2, ar2, h2h, el2, er2);
    agg2_k<<<NN / 2, 128, 0, stream>>>(offs, csr, h2h, el2, er2, b2, out);
}

// Round 9
// 152.571 us; speedup vs baseline: 1.6772x; 1.0547x over previous
//
#include <hip/hip_runtime.h>
#include <hip/hip_fp16.h>

#define NN 50000
#define NE 800000

// bucket sort: bucket = dst >> 8 (256 dsts per bucket)
#define NBK 196                    // ceil(50000/256)
#define BSH 8
#define BMASK 255
#define SCAP 5120                  // >= max bucket population (mean 4082)
#define CHUNK 1024                 // edges per sortA block
#define NBLK_A ((NE + CHUNK - 1) / CHUNK)   // 782
#define NBLK_P ((NN + 63) / 64)             // 782

typedef _Float16 f16x8 __attribute__((ext_vector_type(8)));
typedef float f32x4 __attribute__((ext_vector_type(4)));

// ---------------- K1: init gcur + convert/transpose weights ----------------
__global__ __launch_bounds__(256) void init_k(const float* __restrict__ W1,
                                              const float* __restrict__ W2,
                                              __half* __restrict__ w1t,
                                              __half* __restrict__ w2t,
                                              int* __restrict__ gcur) {
    const int i = blockIdx.x * 256 + threadIdx.x;   // 64 blocks = 16384 = 128*128
    {
        const int k = i >> 7, n = i & 127;
        w1t[n * 128 + k] = __float2half(W1[i]);
    }
    if (i < 128 * 64) {
        const int k = i >> 6, n = i & 63;
        w2t[n * 128 + k] = __float2half(W2[i]);
    }
    if (i < NBK) gcur[i] = 0;
}

// ---------------- K2: fused sortA (bucket binning) + proj1 (MFMA) ----------------
__global__ __launch_bounds__(256) void sortA_proj1_k(const int* __restrict__ src,
                                                     const int* __restrict__ dst,
                                                     const float* __restrict__ wE,
                                                     int* __restrict__ gcur,
                                                     int2* __restrict__ stage,
                                                     const float* __restrict__ x,
                                                     const __half* __restrict__ w1t,
                                                     const float* __restrict__ al1,
                                                     const float* __restrict__ ar1,
                                                     __half* __restrict__ h1h,
                                                     float* __restrict__ el1,
                                                     float* __restrict__ er1) {
    const int t = threadIdx.x;
    if (blockIdx.x < NBLK_A) {
        // ---- sortA ----
        __shared__ int hcnt[NBK], lexcl[NBK], lcur[NBK], gbase[NBK];
        __shared__ int wsum[4];
        __shared__ int2 lbuf[CHUNK];
        const int e0 = blockIdx.x * CHUNK;
        const int ne = min(CHUNK, NE - e0);
        if (t < NBK) { hcnt[t] = 0; lcur[t] = 0; }
        __syncthreads();
        for (int i = t; i < ne; i += 256) atomicAdd(&hcnt[dst[e0 + i] >> BSH], 1);
        __syncthreads();
        {
            const int lane = t & 63, wid = t >> 6;
            const int v = (t < NBK) ? hcnt[t] : 0;
            int s = v;
            #pragma unroll
            for (int off = 1; off < 64; off <<= 1) {
                int u = __shfl_up(s, off, 64);
                if (lane >= off) s += u;
            }
            if (lane == 63) wsum[wid] = s;
            __syncthreads();
            int add = 0;
            for (int w = 0; w < wid; w++) add += wsum[w];
            if (t < NBK) lexcl[t] = s - v + add;
        }
        __syncthreads();
        if (t < NBK && hcnt[t] > 0) gbase[t] = atomicAdd(&gcur[t], hcnt[t]);
        __syncthreads();
        for (int i = t; i < ne; i += 256) {
            const int d = dst[e0 + i];
            const int b = d >> BSH;
            const int r = atomicAdd(&lcur[b], 1);
            lbuf[lexcl[b] + r] = make_int2((src[e0 + i] & 0xFFFF) | ((d & BMASK) << 16),
                                           __float_as_int(wE[e0 + i]));
        }
        __syncthreads();
        const int wv = t >> 6, lane = t & 63;
        for (int b = wv; b < NBK; b += 4) {
            const int cnt = hcnt[b];
            if (cnt == 0) continue;
            const int lo = lexcl[b];
            int2* dp = stage + (size_t)b * SCAP + gbase[b];
            for (int j = lane; j < cnt; j += 64) dp[j] = lbuf[lo + j];
        }
    } else {
        // ---- proj1 (MFMA) ----
        const int bid = blockIdx.x - NBLK_A;
        const int l = t & 63, wv = t >> 6;
        const int rbase = bid * 64 + wv * 16;
        const int cl = l & 15, kg = l >> 4;
        const int arow = rbase + cl;
        const float* xrow = x + (size_t)(arow < NN ? arow : NN - 1) * 128;
        f16x8 afrag[4];
        #pragma unroll
        for (int ks = 0; ks < 4; ks++) {
            const float4 u0 = *(const float4*)(xrow + ks * 32 + kg * 8);
            const float4 u1 = *(const float4*)(xrow + ks * 32 + kg * 8 + 4);
            f16x8 a;
            a[0] = (_Float16)u0.x; a[1] = (_Float16)u0.y; a[2] = (_Float16)u0.z; a[3] = (_Float16)u0.w;
            a[4] = (_Float16)u1.x; a[5] = (_Float16)u1.y; a[6] = (_Float16)u1.z; a[7] = (_Float16)u1.w;
            afrag[ks] = a;
        }
        f32x4 acc[8];
        #pragma unroll
        for (int nt = 0; nt < 8; nt++) { acc[nt][0]=0.f; acc[nt][1]=0.f; acc[nt][2]=0.f; acc[nt][3]=0.f; }
        #pragma unroll
        for (int nt = 0; nt < 8; nt++) {
            const f16x8* bp = (const f16x8*)(w1t + (size_t)(nt * 16 + cl) * 128 + kg * 8);
            #pragma unroll
            for (int ks = 0; ks < 4; ks++)
                acc[nt] = __builtin_amdgcn_mfma_f32_16x16x32_f16(afrag[ks], bp[ks * 4], acc[nt], 0, 0, 0);
        }
        const int orow0 = rbase + kg * 4;
        #pragma unroll
        for (int nt = 0; nt < 8; nt++) {
            const int col = nt * 16 + cl;
            const float alc = al1[col], arc = ar1[col];
            #pragma unroll
            for (int r = 0; r < 4; r++) {
                const float v = acc[nt][r];
                const int orow = orow0 + r;
                const bool ok = (orow < NN);
                if (ok) h1h[(size_t)orow * 128 + col] = __float2half(v);
                float pe = v * alc, pr = v * arc;
                #pragma unroll
                for (int m = 1; m < 16; m <<= 1) {
                    pe += __shfl_xor(pe, m, 64);
                    pr += __shfl_xor(pr, m, 64);
                }
                if (ok && cl == 0) {
                    el1[(size_t)orow * 8 + nt] = pe;
                    er1[(size_t)orow * 8 + nt] = pr;
                }
            }
        }
    }
}

// ---------------- K3: sortB — per-bucket histogram -> offs, scatter to csr ----------------
__global__ __launch_bounds__(1024) void sortB_k(const int* __restrict__ gcur,
                                                const int2* __restrict__ stage,
                                                int* __restrict__ offs,
                                                unsigned int* __restrict__ csr) {
    __shared__ int cnt[256], cur[256], gall[NBK];
    __shared__ int wsum[4];
    __shared__ int sbase;
    const int b = blockIdx.x, t = threadIdx.x;
    if (t < NBK) gall[t] = gcur[t];
    if (t < 256) cnt[t] = 0;
    __syncthreads();
    const int nb = gall[b];
    if (t < 64) {   // wave 0: base = sum gall[0..b)
        int part = 0;
        for (int i = t; i < b; i += 64) part += gall[i];
        #pragma unroll
        for (int m = 1; m < 64; m <<= 1) part += __shfl_xor(part, m, 64);
        if (t == 0) sbase = part;
    }
    const int2* sp = stage + (size_t)b * SCAP;
    for (int i = t; i < nb; i += 1024) atomicAdd(&cnt[(sp[i].x >> 16) & BMASK], 1);
    __syncthreads();
    const int base = sbase;
    const int dlo = b << BSH;
    {   // exclusive scan of cnt[0..256) by threads 0..255
        const int lane = t & 63, wid = t >> 6;
        const int v = (t < 256) ? cnt[t] : 0;
        int s = v;
        #pragma unroll
        for (int off = 1; off < 64; off <<= 1) {
            int u = __shfl_up(s, off, 64);
            if (lane >= off) s += u;
        }
        if (t < 256 && lane == 63) wsum[wid] = s;
        __syncthreads();
        if (t < 256) {
            int add = 0;
            for (int w = 0; w < wid; w++) add += wsum[w];
            const int excl = s - v + add;
            cur[t] = excl;
            if (dlo + t < NN) offs[dlo + t] = base + excl;
        }
        if (b == NBK - 1 && t == 0) offs[NN] = base + nb;
    }
    __syncthreads();
    for (int i = t; i < nb; i += 1024) {
        const int2 pr = sp[i];
        const int dloc = (pr.x >> 16) & BMASK;
        const int sv = pr.x & 0xFFFF;
        const int r = atomicAdd(&cur[dloc], 1);
        const __half hw = __float2half(__int_as_float(pr.y));
        csr[base + r] = (unsigned int)sv | ((unsigned int)__half_as_ushort(hw) << 16);
    }
}

// ---------------- K4: Layer 1 aggregation — 32-edge tiles, csr prefetch, all-shfl ----------------
// logits: head h=l&7, eb=l>>3; lane's edges E'=eb+8k' (k'=0..3), pw kept in flat pwv[k'].
// values: dim-group g=l&15 (head hg=g>>1), es=l>>4; lane's edges E=es+4k (k=0..7).
//   pw[E][hg] lives in lane ((E&7)<<3)|hg = ((es+4*(k&1))<<3)|hg, slot E>>3 = k>>1.
__global__ __launch_bounds__(128) void agg1_k(const int* __restrict__ offs,
                                              const unsigned int* __restrict__ csr,
                                              const __half* __restrict__ h1h,
                                              const float* __restrict__ el1,
                                              const float* __restrict__ er1,
                                              const float* __restrict__ b1,
                                              __half* __restrict__ h2in_h) {
    const int t = threadIdx.x, w = t >> 6, l = t & 63;
    const int n = blockIdx.x * 2 + w;
    const int beg = offs[n], deg = offs[n + 1] - beg;
    const int h = l & 7, eb = l >> 3;
    const int g = l & 15, es = l >> 4, hg = g >> 1;
    const float er_h = er1[(size_t)n * 8 + h];
    float z_lane = 0.f;
    float acc[8];
    #pragma unroll
    for (int j = 0; j < 8; j++) acc[j] = 0.f;
    const float4* hp4 = (const float4*)h1h;

    int pr = 0;
    if (l < 32 && l < deg) pr = (int)csr[beg + l];
    for (int base = 0; base < deg; base += 32) {
        // prefetch next tile's csr
        int prn = 0;
        const int nbase = base + 32;
        if (nbase < deg && l < 32 && nbase + l < deg) prn = (int)csr[beg + nbase + l];
        // logits: this lane's 4 edges (eb+8k') at head h
        float pwv[4];
        #pragma unroll
        for (int k = 0; k < 4; k++) {
            const unsigned int pre = (unsigned int)__shfl(pr, eb + 8 * k, 64);
            float lg = -1e30f;
            if (base + eb + 8 * k < deg) {
                const float v = el1[(size_t)(pre & 0xFFFF) * 8 + h] + er_h;
                lg = v > 0.f ? v : 0.2f * v;
            }
            const float p = __expf(lg);    // 0 for padded slots
            z_lane += p;
            pwv[k] = p * __half2float(__ushort_as_half((unsigned short)(pre >> 16)));
        }
        // values: 8 edges E = es+4k
        int sv[8];
        float pp[8];
        #pragma unroll
        for (int k = 0; k < 8; k++) sv[k] = __shfl(pr, es + 4 * k, 64) & 0xFFFF;
        #pragma unroll
        for (int k = 0; k < 8; k++) {
            const int slane = ((es + 4 * (k & 1)) << 3) | hg;
            pp[k] = __shfl(pwv[k >> 1], slane, 64);
        }
        float4 vv[8];
        #pragma unroll
        for (int k = 0; k < 8; k++) vv[k] = hp4[(size_t)sv[k] * 16 + g];
        #pragma unroll
        for (int k = 0; k < 8; k++) {
            #pragma unroll
            for (int q = 0; q < 4; q++) {
                const float2 f = __half22float2(((const __half2*)&vv[k])[q]);
                acc[2 * q]     = fmaf(pp[k], f.x, acc[2 * q]);
                acc[2 * q + 1] = fmaf(pp[k], f.y, acc[2 * q + 1]);
            }
        }
        pr = prn;
    }
    // z: reduce over eb (bits 3,4,5)
    z_lane += __shfl_xor(z_lane, 8, 64);
    z_lane += __shfl_xor(z_lane, 16, 64);
    z_lane += __shfl_xor(z_lane, 32, 64);
    // acc: reduce over es (bits 4,5)
    #pragma unroll
    for (int j = 0; j < 8; j++) {
        acc[j] += __shfl_xor(acc[j], 16, 64);
        acc[j] += __shfl_xor(acc[j], 32, 64);
    }
    const float zg = __shfl(z_lane, hg, 64);   // lane hg: eb=0, h=hg
    if (l < 16) {
        const float inv = (deg > 0) ? 1.f / zg : 0.f;
        const float4* b4 = (const float4*)b1;
        const float4 bb0 = b4[g * 2], bb1 = b4[g * 2 + 1];
        __half hv[8];
        hv[0] = __float2half(fmaxf(acc[0] * inv + bb0.x, 0.f));
        hv[1] = __float2half(fmaxf(acc[1] * inv + bb0.y, 0.f));
        hv[2] = __float2half(fmaxf(acc[2] * inv + bb0.z, 0.f));
        hv[3] = __float2half(fmaxf(acc[3] * inv + bb0.w, 0.f));
        hv[4] = __float2half(fmaxf(acc[4] * inv + bb1.x, 0.f));
        hv[5] = __float2half(fmaxf(acc[5] * inv + bb1.y, 0.f));
        hv[6] = __float2half(fmaxf(acc[6] * inv + bb1.z, 0.f));
        hv[7] = __float2half(fmaxf(acc[7] * inv + bb1.w, 0.f));
        *(int4*)(h2in_h + (size_t)n * 128 + g * 8) = *(const int4*)hv;
    }
}

// ---------------- K5: Layer 2 projection (MFMA) ----------------
__global__ __launch_bounds__(256) void proj2_k(const __half* __restrict__ xh,
                                               const __half* __restrict__ w2t,
                                               const float* __restrict__ al2,
                                               const float* __restrict__ ar2,
                                               __half* __restrict__ h2h,
                                               float* __restrict__ el2,
                                               float* __restrict__ er2) {
    const int t = threadIdx.x, l = t & 63, wv = t >> 6;
    const int rbase = blockIdx.x * 64 + wv * 16;
    const int cl = l & 15, kg = l >> 4;
    const int arow = rbase + cl;
    const __half* xrow = xh + (size_t)(arow < NN ? arow : NN - 1) * 128;
    f16x8 afrag[4];
    #pragma unroll
    for (int ks = 0; ks < 4; ks++)
        afrag[ks] = *(const f16x8*)(xrow + ks * 32 + kg * 8);
    f32x4 acc[4];
    #pragma unroll
    for (int nt = 0; nt < 4; nt++) { acc[nt][0]=0.f; acc[nt][1]=0.f; acc[nt][2]=0.f; acc[nt][3]=0.f; }
    #pragma unroll
    for (int nt = 0; nt < 4; nt++) {
        const f16x8* bp = (const f16x8*)(w2t + (size_t)(nt * 16 + cl) * 128 + kg * 8);
        #pragma unroll
        for (int ks = 0; ks < 4; ks++)
            acc[nt] = __builtin_amdgcn_mfma_f32_16x16x32_f16(afrag[ks], bp[ks * 4], acc[nt], 0, 0, 0);
    }
    const int orow0 = rbase + kg * 4;
    float pe[4] = {0.f, 0.f, 0.f, 0.f}, pr[4] = {0.f, 0.f, 0.f, 0.f};
    #pragma unroll
    for (int nt = 0; nt < 4; nt++) {
        const int col = nt * 16 + cl;
        const float alc = al2[col], arc = ar2[col];
        #pragma unroll
        for (int r = 0; r < 4; r++) {
            const float v = acc[nt][r];
            const int orow = orow0 + r;
            if (orow < NN) h2h[(size_t)orow * 64 + col] = __float2half(v);
            pe[r] = fmaf(v, alc, pe[r]);
            pr[r] = fmaf(v, arc, pr[r]);
        }
    }
    #pragma unroll
    for (int r = 0; r < 4; r++) {
        #pragma unroll
        for (int m = 1; m < 16; m <<= 1) {
            pe[r] += __shfl_xor(pe[r], m, 64);
            pr[r] += __shfl_xor(pr[r], m, 64);
        }
        const int orow = orow0 + r;
        if (cl == 0 && orow < NN) { el2[orow] = pe[r]; er2[orow] = pr[r]; }
    }
}

// ---------------- K6: Layer 2 aggregation — 32-edge tiles, prefetch ----------------
// logits: lane l<32 owns edge l. values: g=l&7 (8 dims), es=l>>3 (0..7), edges es+8k (k=0..3)
__global__ __launch_bounds__(128) void agg2_k(const int* __restrict__ offs,
                                              const unsigned int* __restrict__ csr,
                                              const __half* __restrict__ h2h,
                                              const float* __restrict__ el2,
                                              const float* __restrict__ er2,
                                              const float* __restrict__ b2,
                                              float* __restrict__ out) {
    const int t = threadIdx.x, w = t >> 6, l = t & 63;
    const int n = blockIdx.x * 2 + w;
    const int beg = offs[n], deg = offs[n + 1] - beg;
    const int g = l & 7, es = l >> 3;
    const float erd = er2[n];
    float z_lane = 0.f;
    float acc[8];
    #pragma unroll
    for (int j = 0; j < 8; j++) acc[j] = 0.f;
    const float4* hp4 = (const float4*)h2h;

    int pr = 0;
    if (l < 32 && l < deg) pr = (int)csr[beg + l];
    for (int base = 0; base < deg; base += 32) {
        int prn = 0;
        const int nbase = base + 32;
        if (nbase < deg && l < 32 && nbase + l < deg) prn = (int)csr[beg + nbase + l];
        float pw = 0.f;
        if (l < 32 && base + l < deg) {
            const float v = el2[(unsigned int)pr & 0xFFFF] + erd;
            const float lg = v > 0.f ? v : 0.2f * v;
            const float p = __expf(lg);
            z_lane += p;
            pw = p * __half2float(__ushort_as_half((unsigned short)((unsigned int)pr >> 16)));
        }
        int sv[4];
        float pp[4];
        #pragma unroll
        for (int k = 0; k < 4; k++) {
            sv[k] = __shfl(pr, es + 8 * k, 64) & 0xFFFF;
            pp[k] = __shfl(pw, es + 8 * k, 64);
        }
        float4 vv[4];
        #pragma unroll
        for (int k = 0; k < 4; k++) vv[k] = hp4[(size_t)sv[k] * 8 + g];
        #pragma unroll
        for (int k = 0; k < 4; k++) {
            #pragma unroll
            for (int q = 0; q < 4; q++) {
                const float2 f = __half22float2(((const __half2*)&vv[k])[q]);
                acc[2 * q]     = fmaf(pp[k], f.x, acc[2 * q]);
                acc[2 * q + 1] = fmaf(pp[k], f.y, acc[2 * q + 1]);
            }
        }
        pr = prn;
    }
    // z: full butterfly (lanes >=32 contribute 0)
    z_lane += __shfl_xor(z_lane, 1, 64);
    z_lane += __shfl_xor(z_lane, 2, 64);
    z_lane += __shfl_xor(z_lane, 4, 64);
    z_lane += __shfl_xor(z_lane, 8, 64);
    z_lane += __shfl_xor(z_lane, 16, 64);
    z_lane += __shfl_xor(z_lane, 32, 64);
    // acc: reduce over es (bits 3,4,5)
    #pragma unroll
    for (int j = 0; j < 8; j++) {
        acc[j] += __shfl_xor(acc[j], 8, 64);
        acc[j] += __shfl_xor(acc[j], 16, 64);
        acc[j] += __shfl_xor(acc[j], 32, 64);
    }
    if (l < 8) {
        const float inv = (deg > 0) ? 1.f / z_lane : 0.f;
        const float4* b4 = (const float4*)b2;
        const float4 bb0 = b4[g * 2], bb1 = b4[g * 2 + 1];
        float4 o0, o1;
        o0.x = acc[0] * inv + bb0.x;
        o0.y = acc[1] * inv + bb0.y;
        o0.z = acc[2] * inv + bb0.z;
        o0.w = acc[3] * inv + bb0.w;
        o1.x = acc[4] * inv + bb1.x;
        o1.y = acc[5] * inv + bb1.y;
        o1.z = acc[6] * inv + bb1.z;
        o1.w = acc[7] * inv + bb1.w;
        float4* op = (float4*)(out + (size_t)n * 64 + g * 8);
        op[0] = o0; op[1] = o1;
    }
}

// ---------------- host ----------------

extern "C" void kernel_launch(void* const* d_in, const int* in_sizes, int n_in,
                              void* d_out, int out_size, void* d_ws, size_t ws_size,
                              hipStream_t stream) {
    const float* feat = (const float*)d_in[0];
    const int*   srcv = (const int*)d_in[1];
    const int*   dstv = (const int*)d_in[2];
    const float* wE   = (const float*)d_in[3];
    const float* W1   = (const float*)d_in[4];
    const float* al1  = (const float*)d_in[5];
    const float* ar1  = (const float*)d_in[6];
    const float* b1   = (const float*)d_in[7];
    const float* W2   = (const float*)d_in[8];
    const float* al2  = (const float*)d_in[9];
    const float* ar2  = (const float*)d_in[10];
    const float* b2   = (const float*)d_in[11];
    float* out = (float*)d_out;

    char* ws = (char*)d_ws;
    size_t off = 0;
    auto take = [&](size_t bytes) -> char* {
        char* pp = ws + off;
        off = (off + bytes + 255) & ~(size_t)255;
        return pp;
    };
    __half* h1h   = (__half*)take((size_t)NN * 128 * 2);
    __half* h2h   = (__half*)take((size_t)NN * 64 * 2);
    __half* h2in_h= (__half*)take((size_t)NN * 128 * 2);   // 12.8 MB; first ~8 MB aliased as sort staging
    float* el1  = (float*)take((size_t)NN * 8 * 4);
    float* er1  = (float*)take((size_t)NN * 8 * 4);
    float* el2  = (float*)take((size_t)NN * 4);
    float* er2  = (float*)take((size_t)NN * 4);
    int* offs   = (int*)take((size_t)(NN + 1) * 4);
    unsigned int* csr = (unsigned int*)take((size_t)NE * 4);
    int* gcur   = (int*)take((size_t)NBK * 4);
    __half* w1t = (__half*)take((size_t)128 * 128 * 2);
    __half* w2t = (__half*)take((size_t)64 * 128 * 2);
    int2* stage = (int2*)h2in_h;   // NBK*SCAP*8 = 8.03 MB, consumed (sortB) before agg1 writes h2in_h

    init_k<<<64, 256, 0, stream>>>(W1, W2, w1t, w2t, gcur);
    sortA_proj1_k<<<NBLK_A + NBLK_P, 256, 0, stream>>>(srcv, dstv, wE, gcur, stage,
                                                       feat, w1t, al1, ar1, h1h, el1, er1);
    sortB_k<<<NBK, 1024, 0, stream>>>(gcur, stage, offs, csr);
    agg1_k<<<NN / 2, 128, 0, stream>>>(offs, csr, h1h, el1, er1, b1, h2in_h);
    proj2_k<<<(NN + 63) / 64, 256, 0, stream>>>(h2in_h, w2t, al2, ar2, h2h, el2, er2);
    agg2_k<<<NN / 2, 128, 0, stream>>>(offs, csr, h2h, el2, er2, b2, out);
}

// Round 10
// 140.853 us; speedup vs baseline: 1.8167x; 1.0832x over previous
//
#include <hip/hip_runtime.h>
#include <hip/hip_fp16.h>

#define NN 50000
#define NE 800000

// bucket sort: bucket = dst >> 8 (256 dsts per bucket)
#define NBK 196                    // ceil(50000/256)
#define BSH 8
#define BMASK 255
#define SCAP 5120                  // >= max bucket population (mean 4082, +16 sigma)
#define CHUNK 2048                 // edges per sortA block
#define NBLK_A ((NE + CHUNK - 1) / CHUNK)   // 391
#define NBLK_P ((NN + 63) / 64)             // 782
#define GPAD 4                     // gcur stride = 16 ints = 64 B (1 line per counter)

typedef _Float16 f16x8 __attribute__((ext_vector_type(8)));
typedef float f32x4 __attribute__((ext_vector_type(4)));

// ---------------- K1: init gcur + convert/transpose weights ----------------
__global__ __launch_bounds__(256) void init_k(const float* __restrict__ W1,
                                              const float* __restrict__ W2,
                                              __half* __restrict__ w1t,
                                              __half* __restrict__ w2t,
                                              int* __restrict__ gcur) {
    const int i = blockIdx.x * 256 + threadIdx.x;   // 64 blocks = 16384 = 128*128
    {
        const int k = i >> 7, n = i & 127;
        w1t[n * 128 + k] = __float2half(W1[i]);
    }
    if (i < 128 * 64) {
        const int k = i >> 6, n = i & 63;
        w2t[n * 128 + k] = __float2half(W2[i]);
    }
    if (i < NBK) gcur[i << GPAD] = 0;
}

// ---------------- K2: fused sortA (bucket binning) + proj1 (MFMA) ----------------
__global__ __launch_bounds__(256) void sortA_proj1_k(const int* __restrict__ src,
                                                     const int* __restrict__ dst,
                                                     const float* __restrict__ wE,
                                                     int* __restrict__ gcur,
                                                     int2* __restrict__ stage,
                                                     const float* __restrict__ x,
                                                     const __half* __restrict__ w1t,
                                                     const float* __restrict__ al1,
                                                     const float* __restrict__ ar1,
                                                     __half* __restrict__ h1h,
                                                     float* __restrict__ el1,
                                                     float* __restrict__ er1) {
    const int t = threadIdx.x;
    if (blockIdx.x < NBLK_A) {
        // ---- sortA ----
        __shared__ int hcnt[NBK], lexcl[NBK], lcur[NBK], gbase[NBK];
        __shared__ int wsum[4];
        __shared__ int2 lbuf[CHUNK];
        const int e0 = blockIdx.x * CHUNK;
        const int ne = min(CHUNK, NE - e0);
        if (t < NBK) { hcnt[t] = 0; lcur[t] = 0; }
        __syncthreads();
        for (int i = t; i < ne; i += 256) atomicAdd(&hcnt[dst[e0 + i] >> BSH], 1);
        __syncthreads();
        {
            const int lane = t & 63, wid = t >> 6;
            const int v = (t < NBK) ? hcnt[t] : 0;
            int s = v;
            #pragma unroll
            for (int off = 1; off < 64; off <<= 1) {
                int u = __shfl_up(s, off, 64);
                if (lane >= off) s += u;
            }
            if (lane == 63) wsum[wid] = s;
            __syncthreads();
            int add = 0;
            for (int w = 0; w < wid; w++) add += wsum[w];
            if (t < NBK) lexcl[t] = s - v + add;
        }
        __syncthreads();
        if (t < NBK && hcnt[t] > 0) gbase[t] = atomicAdd(&gcur[t << GPAD], hcnt[t]);
        __syncthreads();
        for (int i = t; i < ne; i += 256) {
            const int d = dst[e0 + i];
            const int b = d >> BSH;
            const int r = atomicAdd(&lcur[b], 1);
            lbuf[lexcl[b] + r] = make_int2((src[e0 + i] & 0xFFFF) | ((d & BMASK) << 16),
                                           __float_as_int(wE[e0 + i]));
        }
        __syncthreads();
        const int wv = t >> 6, lane = t & 63;
        for (int b = wv; b < NBK; b += 4) {
            const int cnt = hcnt[b];
            if (cnt == 0) continue;
            const int lo = lexcl[b];
            int2* dp = stage + (size_t)b * SCAP + gbase[b];
            for (int j = lane; j < cnt; j += 64) dp[j] = lbuf[lo + j];
        }
    } else {
        // ---- proj1 (MFMA) ----
        const int bid = blockIdx.x - NBLK_A;
        const int l = t & 63, wv = t >> 6;
        const int rbase = bid * 64 + wv * 16;
        const int cl = l & 15, kg = l >> 4;
        const int arow = rbase + cl;
        const float* xrow = x + (size_t)(arow < NN ? arow : NN - 1) * 128;
        f16x8 afrag[4];
        #pragma unroll
        for (int ks = 0; ks < 4; ks++) {
            const float4 u0 = *(const float4*)(xrow + ks * 32 + kg * 8);
            const float4 u1 = *(const float4*)(xrow + ks * 32 + kg * 8 + 4);
            f16x8 a;
            a[0] = (_Float16)u0.x; a[1] = (_Float16)u0.y; a[2] = (_Float16)u0.z; a[3] = (_Float16)u0.w;
            a[4] = (_Float16)u1.x; a[5] = (_Float16)u1.y; a[6] = (_Float16)u1.z; a[7] = (_Float16)u1.w;
            afrag[ks] = a;
        }
        f32x4 acc[8];
        #pragma unroll
        for (int nt = 0; nt < 8; nt++) { acc[nt][0]=0.f; acc[nt][1]=0.f; acc[nt][2]=0.f; acc[nt][3]=0.f; }
        #pragma unroll
        for (int nt = 0; nt < 8; nt++) {
            const f16x8* bp = (const f16x8*)(w1t + (size_t)(nt * 16 + cl) * 128 + kg * 8);
            #pragma unroll
            for (int ks = 0; ks < 4; ks++)
                acc[nt] = __builtin_amdgcn_mfma_f32_16x16x32_f16(afrag[ks], bp[ks * 4], acc[nt], 0, 0, 0);
        }
        const int orow0 = rbase + kg * 4;
        #pragma unroll
        for (int nt = 0; nt < 8; nt++) {
            const int col = nt * 16 + cl;
            const float alc = al1[col], arc = ar1[col];
            #pragma unroll
            for (int r = 0; r < 4; r++) {
                const float v = acc[nt][r];
                const int orow = orow0 + r;
                const bool ok = (orow < NN);
                if (ok) h1h[(size_t)orow * 128 + col] = __float2half(v);
                float pe = v * alc, pr = v * arc;
                #pragma unroll
                for (int m = 1; m < 16; m <<= 1) {
                    pe += __shfl_xor(pe, m, 64);
                    pr += __shfl_xor(pr, m, 64);
                }
                if (ok && cl == 0) {
                    el1[(size_t)orow * 8 + nt] = pe;
                    er1[(size_t)orow * 8 + nt] = pr;
                }
            }
        }
    }
}

// ---------------- K3: sortB — per-bucket histogram -> offs, scatter to csr ----------------
__global__ __launch_bounds__(1024) void sortB_k(const int* __restrict__ gcur,
                                                const int2* __restrict__ stage,
                                                int* __restrict__ offs,
                                                unsigned int* __restrict__ csr) {
    __shared__ int cnt[256], cur[256], gall[NBK];
    __shared__ int wsum[4];
    __shared__ int sbase;
    const int b = blockIdx.x, t = threadIdx.x;
    if (t < NBK) gall[t] = gcur[t << GPAD];
    if (t < 256) cnt[t] = 0;
    __syncthreads();
    const int nb = gall[b];
    if (t < 64) {   // wave 0: base = sum gall[0..b)
        int part = 0;
        for (int i = t; i < b; i += 64) part += gall[i];
        #pragma unroll
        for (int m = 1; m < 64; m <<= 1) part += __shfl_xor(part, m, 64);
        if (t == 0) sbase = part;
    }
    const int2* sp = stage + (size_t)b * SCAP;
    for (int i = t; i < nb; i += 1024) atomicAdd(&cnt[(sp[i].x >> 16) & BMASK], 1);
    __syncthreads();
    const int base = sbase;
    const int dlo = b << BSH;
    {   // exclusive scan of cnt[0..256) by threads 0..255
        const int lane = t & 63, wid = t >> 6;
        const int v = (t < 256) ? cnt[t] : 0;
        int s = v;
        #pragma unroll
        for (int off = 1; off < 64; off <<= 1) {
            int u = __shfl_up(s, off, 64);
            if (lane >= off) s += u;
        }
        if (t < 256 && lane == 63) wsum[wid] = s;
        __syncthreads();
        if (t < 256) {
            int add = 0;
            for (int w = 0; w < wid; w++) add += wsum[w];
            const int excl = s - v + add;
            cur[t] = excl;
            if (dlo + t < NN) offs[dlo + t] = base + excl;
        }
        if (b == NBK - 1 && t == 0) offs[NN] = base + nb;
    }
    __syncthreads();
    for (int i = t; i < nb; i += 1024) {
        const int2 pr = sp[i];
        const int dloc = (pr.x >> 16) & BMASK;
        const int sv = pr.x & 0xFFFF;
        const int r = atomicAdd(&cur[dloc], 1);
        const __half hw = __float2half(__int_as_float(pr.y));
        csr[base + r] = (unsigned int)sv | ((unsigned int)__half_as_ushort(hw) << 16);
    }
}

// ---------------- K4: Layer 1 aggregation — 32-edge tiles, csr prefetch, all-shfl ----------------
// logits: head h=l&7, eb=l>>3; lane's edges E'=eb+8k' (k'=0..3), pw kept in flat pwv[k'].
// values: dim-group g=l&15 (head hg=g>>1), es=l>>4; lane's edges E=es+4k (k=0..7).
//   pw[E][hg] lives in lane ((E&7)<<3)|hg = ((es+4*(k&1))<<3)|hg, slot E>>3 = k>>1.
__global__ __launch_bounds__(128) void agg1_k(const int* __restrict__ offs,
                                              const unsigned int* __restrict__ csr,
                                              const __half* __restrict__ h1h,
                                              const float* __restrict__ el1,
                                              const float* __restrict__ er1,
                                              const float* __restrict__ b1,
                                              __half* __restrict__ h2in_h) {
    const int t = threadIdx.x, w = t >> 6, l = t & 63;
    const int n = blockIdx.x * 2 + w;
    const int beg = offs[n], deg = offs[n + 1] - beg;
    const int h = l & 7, eb = l >> 3;
    const int g = l & 15, es = l >> 4, hg = g >> 1;
    const float er_h = er1[(size_t)n * 8 + h];
    float z_lane = 0.f;
    float acc[8];
    #pragma unroll
    for (int j = 0; j < 8; j++) acc[j] = 0.f;
    const float4* hp4 = (const float4*)h1h;

    int pr = 0;
    if (l < 32 && l < deg) pr = (int)csr[beg + l];
    for (int base = 0; base < deg; base += 32) {
        // prefetch next tile's csr
        int prn = 0;
        const int nbase = base + 32;
        if (nbase < deg && l < 32 && nbase + l < deg) prn = (int)csr[beg + nbase + l];
        // logits: this lane's 4 edges (eb+8k') at head h
        float pwv[4];
        #pragma unroll
        for (int k = 0; k < 4; k++) {
            const unsigned int pre = (unsigned int)__shfl(pr, eb + 8 * k, 64);
            float lg = -1e30f;
            if (base + eb + 8 * k < deg) {
                const float v = el1[(size_t)(pre & 0xFFFF) * 8 + h] + er_h;
                lg = v > 0.f ? v : 0.2f * v;
            }
            const float p = __expf(lg);    // 0 for padded slots
            z_lane += p;
            pwv[k] = p * __half2float(__ushort_as_half((unsigned short)(pre >> 16)));
        }
        // values: 8 edges E = es+4k
        int sv[8];
        float pp[8];
        #pragma unroll
        for (int k = 0; k < 8; k++) sv[k] = __shfl(pr, es + 4 * k, 64) & 0xFFFF;
        #pragma unroll
        for (int k = 0; k < 8; k++) {
            const int slane = ((es + 4 * (k & 1)) << 3) | hg;
            pp[k] = __shfl(pwv[k >> 1], slane, 64);
        }
        float4 vv[8];
        #pragma unroll
        for (int k = 0; k < 8; k++) vv[k] = hp4[(size_t)sv[k] * 16 + g];
        #pragma unroll
        for (int k = 0; k < 8; k++) {
            #pragma unroll
            for (int q = 0; q < 4; q++) {
                const float2 f = __half22float2(((const __half2*)&vv[k])[q]);
                acc[2 * q]     = fmaf(pp[k], f.x, acc[2 * q]);
                acc[2 * q + 1] = fmaf(pp[k], f.y, acc[2 * q + 1]);
            }
        }
        pr = prn;
    }
    // z: reduce over eb (bits 3,4,5)
    z_lane += __shfl_xor(z_lane, 8, 64);
    z_lane += __shfl_xor(z_lane, 16, 64);
    z_lane += __shfl_xor(z_lane, 32, 64);
    // acc: reduce over es (bits 4,5)
    #pragma unroll
    for (int j = 0; j < 8; j++) {
        acc[j] += __shfl_xor(acc[j], 16, 64);
        acc[j] += __shfl_xor(acc[j], 32, 64);
    }
    const float zg = __shfl(z_lane, hg, 64);   // lane hg: eb=0, h=hg
    if (l < 16) {
        const float inv = (deg > 0) ? 1.f / zg : 0.f;
        const float4* b4 = (const float4*)b1;
        const float4 bb0 = b4[g * 2], bb1 = b4[g * 2 + 1];
        __half hv[8];
        hv[0] = __float2half(fmaxf(acc[0] * inv + bb0.x, 0.f));
        hv[1] = __float2half(fmaxf(acc[1] * inv + bb0.y, 0.f));
        hv[2] = __float2half(fmaxf(acc[2] * inv + bb0.z, 0.f));
        hv[3] = __float2half(fmaxf(acc[3] * inv + bb0.w, 0.f));
        hv[4] = __float2half(fmaxf(acc[4] * inv + bb1.x, 0.f));
        hv[5] = __float2half(fmaxf(acc[5] * inv + bb1.y, 0.f));
        hv[6] = __float2half(fmaxf(acc[6] * inv + bb1.z, 0.f));
        hv[7] = __float2half(fmaxf(acc[7] * inv + bb1.w, 0.f));
        *(int4*)(h2in_h + (size_t)n * 128 + g * 8) = *(const int4*)hv;
    }
}

// ---------------- K5: Layer 2 projection (MFMA) ----------------
__global__ __launch_bounds__(256) void proj2_k(const __half* __restrict__ xh,
                                               const __half* __restrict__ w2t,
                                               const float* __restrict__ al2,
                                               const float* __restrict__ ar2,
                                               __half* __restrict__ h2h,
                                               float* __restrict__ el2,
                                               float* __restrict__ er2) {
    const int t = threadIdx.x, l = t & 63, wv = t >> 6;
    const int rbase = blockIdx.x * 64 + wv * 16;
    const int cl = l & 15, kg = l >> 4;
    const int arow = rbase + cl;
    const __half* xrow = xh + (size_t)(arow < NN ? arow : NN - 1) * 128;
    f16x8 afrag[4];
    #pragma unroll
    for (int ks = 0; ks < 4; ks++)
        afrag[ks] = *(const f16x8*)(xrow + ks * 32 + kg * 8);
    f32x4 acc[4];
    #pragma unroll
    for (int nt = 0; nt < 4; nt++) { acc[nt][0]=0.f; acc[nt][1]=0.f; acc[nt][2]=0.f; acc[nt][3]=0.f; }
    #pragma unroll
    for (int nt = 0; nt < 4; nt++) {
        const f16x8* bp = (const f16x8*)(w2t + (size_t)(nt * 16 + cl) * 128 + kg * 8);
        #pragma unroll
        for (int ks = 0; ks < 4; ks++)
            acc[nt] = __builtin_amdgcn_mfma_f32_16x16x32_f16(afrag[ks], bp[ks * 4], acc[nt], 0, 0, 0);
    }
    const int orow0 = rbase + kg * 4;
    float pe[4] = {0.f, 0.f, 0.f, 0.f}, pr[4] = {0.f, 0.f, 0.f, 0.f};
    #pragma unroll
    for (int nt = 0; nt < 4; nt++) {
        const int col = nt * 16 + cl;
        const float alc = al2[col], arc = ar2[col];
        #pragma unroll
        for (int r = 0; r < 4; r++) {
            const float v = acc[nt][r];
            const int orow = orow0 + r;
            if (orow < NN) h2h[(size_t)orow * 64 + col] = __float2half(v);
            pe[r] = fmaf(v, alc, pe[r]);
            pr[r] = fmaf(v, arc, pr[r]);
        }
    }
    #pragma unroll
    for (int r = 0; r < 4; r++) {
        #pragma unroll
        for (int m = 1; m < 16; m <<= 1) {
            pe[r] += __shfl_xor(pe[r], m, 64);
            pr[r] += __shfl_xor(pr[r], m, 64);
        }
        const int orow = orow0 + r;
        if (cl == 0 && orow < NN) { el2[orow] = pe[r]; er2[orow] = pr[r]; }
    }
}

// ---------------- K6: Layer 2 aggregation — 32-edge tiles, prefetch ----------------
// logits: lane l<32 owns edge l. values: g=l&7 (8 dims), es=l>>3 (0..7), edges es+8k (k=0..3)
__global__ __launch_bounds__(128) void agg2_k(const int* __restrict__ offs,
                                              const unsigned int* __restrict__ csr,
                                              const __half* __restrict__ h2h,
                                              const float* __restrict__ el2,
                                              const float* __restrict__ er2,
                                              const float* __restrict__ b2,
                                              float* __restrict__ out) {
    const int t = threadIdx.x, w = t >> 6, l = t & 63;
    const int n = blockIdx.x * 2 + w;
    const int beg = offs[n], deg = offs[n + 1] - beg;
    const int g = l & 7, es = l >> 3;
    const float erd = er2[n];
    float z_lane = 0.f;
    float acc[8];
    #pragma unroll
    for (int j = 0; j < 8; j++) acc[j] = 0.f;
    const float4* hp4 = (const float4*)h2h;

    int pr = 0;
    if (l < 32 && l < deg) pr = (int)csr[beg + l];
    for (int base = 0; base < deg; base += 32) {
        int prn = 0;
        const int nbase = base + 32;
        if (nbase < deg && l < 32 && nbase + l < deg) prn = (int)csr[beg + nbase + l];
        float pw = 0.f;
        if (l < 32 && base + l < deg) {
            const float v = el2[(unsigned int)pr & 0xFFFF] + erd;
            const float lg = v > 0.f ? v : 0.2f * v;
            const float p = __expf(lg);
            z_lane += p;
            pw = p * __half2float(__ushort_as_half((unsigned short)((unsigned int)pr >> 16)));
        }
        int sv[4];
        float pp[4];
        #pragma unroll
        for (int k = 0; k < 4; k++) {
            sv[k] = __shfl(pr, es + 8 * k, 64) & 0xFFFF;
            pp[k] = __shfl(pw, es + 8 * k, 64);
        }
        float4 vv[4];
        #pragma unroll
        for (int k = 0; k < 4; k++) vv[k] = hp4[(size_t)sv[k] * 8 + g];
        #pragma unroll
        for (int k = 0; k < 4; k++) {
            #pragma unroll
            for (int q = 0; q < 4; q++) {
                const float2 f = __half22float2(((const __half2*)&vv[k])[q]);
                acc[2 * q]     = fmaf(pp[k], f.x, acc[2 * q]);
                acc[2 * q + 1] = fmaf(pp[k], f.y, acc[2 * q + 1]);
            }
        }
        pr = prn;
    }
    // z: full butterfly (lanes >=32 contribute 0)
    z_lane += __shfl_xor(z_lane, 1, 64);
    z_lane += __shfl_xor(z_lane, 2, 64);
    z_lane += __shfl_xor(z_lane, 4, 64);
    z_lane += __shfl_xor(z_lane, 8, 64);
    z_lane += __shfl_xor(z_lane, 16, 64);
    z_lane += __shfl_xor(z_lane, 32, 64);
    // acc: reduce over es (bits 3,4,5)
    #pragma unroll
    for (int j = 0; j < 8; j++) {
        acc[j] += __shfl_xor(acc[j], 8, 64);
        acc[j] += __shfl_xor(acc[j], 16, 64);
        acc[j] += __shfl_xor(acc[j], 32, 64);
    }
    if (l < 8) {
        const float inv = (deg > 0) ? 1.f / z_lane : 0.f;
        const float4* b4 = (const float4*)b2;
        const float4 bb0 = b4[g * 2], bb1 = b4[g * 2 + 1];
        float4 o0, o1;
        o0.x = acc[0] * inv + bb0.x;
        o0.y = acc[1] * inv + bb0.y;
        o0.z = acc[2] * inv + bb0.z;
        o0.w = acc[3] * inv + bb0.w;
        o1.x = acc[4] * inv + bb1.x;
        o1.y = acc[5] * inv + bb1.y;
        o1.z = acc[6] * inv + bb1.z;
        o1.w = acc[7] * inv + bb1.w;
        float4* op = (float4*)(out + (size_t)n * 64 + g * 8);
        op[0] = o0; op[1] = o1;
    }
}

// ---------------- host ----------------

extern "C" void kernel_launch(void* const* d_in, const int* in_sizes, int n_in,
                              void* d_out, int out_size, void* d_ws, size_t ws_size,
                              hipStream_t stream) {
    const float* feat = (const float*)d_in[0];
    const int*   srcv = (const int*)d_in[1];
    const int*   dstv = (const int*)d_in[2];
    const float* wE   = (const float*)d_in[3];
    const float* W1   = (const float*)d_in[4];
    const float* al1  = (const float*)d_in[5];
    const float* ar1  = (const float*)d_in[6];
    const float* b1   = (const float*)d_in[7];
    const float* W2   = (const float*)d_in[8];
    const float* al2  = (const float*)d_in[9];
    const float* ar2  = (const float*)d_in[10];
    const float* b2   = (const float*)d_in[11];
    float* out = (float*)d_out;

    char* ws = (char*)d_ws;
    size_t off = 0;
    auto take = [&](size_t bytes) -> char* {
        char* pp = ws + off;
        off = (off + bytes + 255) & ~(size_t)255;
        return pp;
    };
    __half* h1h   = (__half*)take((size_t)NN * 128 * 2);
    __half* h2h   = (__half*)take((size_t)NN * 64 * 2);
    __half* h2in_h= (__half*)take((size_t)NN * 128 * 2);   // 12.8 MB; first ~8 MB aliased as sort staging
    float* el1  = (float*)take((size_t)NN * 8 * 4);
    float* er1  = (float*)take((size_t)NN * 8 * 4);
    float* el2  = (float*)take((size_t)NN * 4);
    float* er2  = (float*)take((size_t)NN * 4);
    int* offs   = (int*)take((size_t)(NN + 1) * 4);
    unsigned int* csr = (unsigned int*)take((size_t)NE * 4);
    int* gcur   = (int*)take((size_t)(NBK << GPAD) * 4);
    __half* w1t = (__half*)take((size_t)128 * 128 * 2);
    __half* w2t = (__half*)take((size_t)64 * 128 * 2);
    int2* stage = (int2*)h2in_h;   // NBK*SCAP*8 = 8.03 MB, consumed (sortB) before agg1 writes h2in_h

    init_k<<<64, 256, 0, stream>>>(W1, W2, w1t, w2t, gcur);
    sortA_proj1_k<<<NBLK_A + NBLK_P, 256, 0, stream>>>(srcv, dstv, wE, gcur, stage,
                                                       feat, w1t, al1, ar1, h1h, el1, er1);
    sortB_k<<<NBK, 1024, 0, stream>>>(gcur, stage, offs, csr);
    agg1_k<<<NN / 2, 128, 0, stream>>>(offs, csr, h1h, el1, er1, b1, h2in_h);
    proj2_k<<<(NN + 63) / 64, 256, 0, stream>>>(h2in_h, w2t, al2, ar2, h2h, el2, er2);
    agg2_k<<<NN / 2, 128, 0, stream>>>(offs, csr, h2h, el2, er2, b2, out);
}